// Round 14
// baseline (465.449 us; speedup 1.0000x reference)
//
#include <hip/hip_runtime.h>

#define N_NODES 100000
#define N_EDGES 3200000
#define D 64
#define EPS 1e-5f

#define BSHIFT 7
#define BNODES 128                                          // nodes per bucket
#define NBUCK ((N_NODES + BNODES - 1) / BNODES)             // 782
#define P1_CHUNK 4096
#define NB_P1 ((N_EDGES + P1_CHUNK - 1) / P1_CHUNK)         // 782
#define SRC_MASK 0x1FFFFu                                   // 17 bits >= 100000
#define BCAP 4480                                           // bucket region cap
#define TBL_STRIDE 784                                      // 783 entries + pad
#define NGB ((N_NODES + 127) / 128)                         // 782 gemm blocks

typedef __attribute__((ext_vector_type(8))) short bf16x8;   // 8 bf16 = 4 VGPRs
typedef __attribute__((ext_vector_type(4))) float f32x4;

__device__ __forceinline__ unsigned short f2bf(float f) {
  unsigned int u = __float_as_uint(f);
  u += 0x7FFFu + ((u >> 16) & 1u);          // round to nearest even
  return (unsigned short)(u >> 16);
}
__device__ __forceinline__ float bf2f(unsigned short h) {
  return __uint_as_float(((unsigned int)h) << 16);
}
__device__ __forceinline__ float2 bfpair(unsigned int u) {
  return make_float2(__uint_as_float(u << 16), __uint_as_float(u & 0xFFFF0000u));
}
__device__ __forceinline__ void addp(float2 a[4], uint4 u) {
  a[0] += bfpair(u.x);
  a[1] += bfpair(u.y);
  a[2] += bfpair(u.z);
  a[3] += bfpair(u.w);
}

// ---------------------------------------------------------------------------
// Pass 1 (+ weight fold): blocks [0, NB_P1) partition a 4096-edge chunk by
// 128-node bucket (block-local counting sort, coalesced out). Blocks
// NB_P1+{0,1} fold GCNConv+FC weights of layer 1/2 into MFMA-B-swizzled bf16.
// ---------------------------------------------------------------------------
__global__ __launch_bounds__(256) void pass1_sort(
    const int* __restrict__ src, const int* __restrict__ dst,
    unsigned int* __restrict__ stage, unsigned short* __restrict__ tbl,
    const float* __restrict__ W1, const float* __restrict__ b1,
    const float* __restrict__ fw1, const float* __restrict__ fb1,
    const float* __restrict__ W2, const float* __restrict__ b2,
    const float* __restrict__ fw2, const float* __restrict__ fb2,
    unsigned int* __restrict__ WcB1, float* __restrict__ bc1,
    unsigned int* __restrict__ WcB2, float* __restrict__ bc2) {
  __shared__ union {
    struct { unsigned int hist[NBUCK]; unsigned int ts[256]; unsigned int sorted[P1_CHUNK]; } p;
    struct { float sW[4096]; float sfT[65 * 64]; } c;   // sfT padded: col reads bank-clean
  } sm;
  const int tid = threadIdx.x;

  if (blockIdx.x >= NB_P1) {                 // ---- weight-fold path ----
    const int layer = blockIdx.x - NB_P1;
    const float* W  = layer ? W2  : W1;
    const float* fw = layer ? fw2 : fw1;
    const float* b  = layer ? b2  : b1;
    const float* fb = layer ? fb2 : fb1;
    unsigned int* WcB = layer ? WcB2 : WcB1;
    float* bc = layer ? bc2 : bc1;

    for (int i = tid; i < 4096; i += 256) {
      sm.c.sW[i] = W[i];
      int t = i >> 6, n = i & 63;
      sm.c.sfT[n * 65 + t] = fw[i];          // transposed+padded
    }
    __syncthreads();
    for (int o = tid; o < 2048; o += 256) {
      int jj = o & 3, L = (o >> 2) & 63, kh = (o >> 8) & 1, nt = o >> 9;
      int k0 = (L >> 4) * 8 + jj * 2 + kh * 32;
      int n  = nt * 16 + (L & 15);
      float d0 = 0.f, d1 = 0.f;
      #pragma unroll
      for (int t = 0; t < 64; ++t) {
        float f = sm.c.sfT[n * 65 + t];
        d0 += sm.c.sW[k0 * 64 + t] * f;
        d1 += sm.c.sW[(k0 + 1) * 64 + t] * f;
      }
      WcB[o] = ((unsigned)f2bf(d1) << 16) | f2bf(d0);
    }
    if (tid < 64) {
      float acc = fb[tid];
      #pragma unroll
      for (int k = 0; k < 64; ++k) acc += b[k] * sm.c.sfT[tid * 65 + k];
      bc[tid] = acc;
    }
    return;
  }

  // ---- partition path ----
  const int e0 = blockIdx.x * P1_CHUNK;
  for (int b = tid; b < NBUCK; b += 256) sm.p.hist[b] = 0;
  __syncthreads();

  int dreg[16];
  #pragma unroll
  for (int k = 0; k < 16; ++k) {
    int e = e0 + k * 256 + tid;
    int d = (e < N_EDGES) ? dst[e] : -1;
    dreg[k] = d;
    if (d >= 0) atomicAdd(&sm.p.hist[((unsigned)d) >> BSHIFT], 1u);
  }
  __syncthreads();

  unsigned int v[4], run = 0;
  #pragma unroll
  for (int j = 0; j < 4; ++j) {
    int bk = 4 * tid + j;
    unsigned int h = (bk < NBUCK) ? sm.p.hist[bk] : 0u;
    v[j] = run;
    run += h;
  }
  sm.p.ts[tid] = run;
  __syncthreads();
  for (int o = 1; o < 256; o <<= 1) {
    unsigned int add = (tid >= o) ? sm.p.ts[tid - o] : 0u;
    __syncthreads();
    sm.p.ts[tid] += add;
    __syncthreads();
  }
  const unsigned int excl = sm.p.ts[tid] - run;
  const unsigned int m = sm.p.ts[255];
  unsigned short* trow = tbl + (size_t)blockIdx.x * TBL_STRIDE;
  #pragma unroll
  for (int j = 0; j < 4; ++j) {
    int bk = 4 * tid + j;
    if (bk < NBUCK) {
      unsigned int o = excl + v[j];
      sm.p.hist[bk] = o;
      trow[bk] = (unsigned short)o;
    }
  }
  if (tid == 0) trow[NBUCK] = (unsigned short)m;
  __syncthreads();

  #pragma unroll
  for (int k = 0; k < 16; ++k) {
    int e = e0 + k * 256 + tid;
    int t = dreg[k];
    if (t >= 0) {
      unsigned int pos = atomicAdd(&sm.p.hist[((unsigned)t) >> BSHIFT], 1u);
      sm.p.sorted[pos] = (((unsigned)(t & (BNODES - 1))) << 17) | (unsigned)src[e];
    }
  }
  __syncthreads();

  unsigned int* so = stage + (size_t)blockIdx.x * P1_CHUNK;
  for (int i = tid; i < (int)m; i += 256) so[i] = sm.p.sorted[i];
}

// ---------------------------------------------------------------------------
// Pass 2: paired-segment gather -> LDS counting sort to node CSR + fused
// layer-1 prescale. Block 0 additionally zeroes stats[2048] + barrier ctr[2].
// ---------------------------------------------------------------------------
__global__ __launch_bounds__(512) void pass2_sort(
    const unsigned int* __restrict__ stage, const unsigned short* __restrict__ tbl,
    int* __restrict__ eSrc, int* __restrict__ off, int* __restrict__ edeg,
    float* __restrict__ dinv, const float* __restrict__ x,
    unsigned short* __restrict__ Xs, float* __restrict__ statsZ,
    int* __restrict__ ctrZ) {
  __shared__ int spre[512];
  __shared__ int cnt[BNODES];
  __shared__ int ts[BNODES];
  __shared__ float dinvL[BNODES];
  __shared__ unsigned int raw[BCAP];
  __shared__ int sorted[BCAP];
  const int b = blockIdx.x, tid = threadIdx.x;
  const int n0 = b * BNODES;

  if (b == 0) {
    #pragma unroll
    for (int k = 0; k < 4; ++k) statsZ[tid * 4 + k] = 0.0f;  // 2048 floats
    if (tid < 2) ctrZ[tid] = 0;
  }

  int base0 = 0, base1 = 0, len0 = 0, len1 = 0;
  {
    int s0 = 2 * tid, s1 = 2 * tid + 1;
    if (s0 < NB_P1) {
      const unsigned short* trow = tbl + (size_t)s0 * TBL_STRIDE;
      int o0 = trow[b], o1 = trow[b + 1];
      base0 = s0 * P1_CHUNK + o0;
      len0 = o1 - o0;
    }
    if (s1 < NB_P1) {
      const unsigned short* trow = tbl + (size_t)s1 * TBL_STRIDE;
      int o0 = trow[b], o1 = trow[b + 1];
      base1 = s1 * P1_CHUNK + o0;
      len1 = o1 - o0;
    }
  }
  if (tid < BNODES) cnt[tid] = 0;
  const int mylen = len0 + len1;
  spre[tid] = mylen;
  __syncthreads();
  for (int o = 1; o < 512; o <<= 1) {
    int add = (tid >= o) ? spre[tid - o] : 0;
    __syncthreads();
    spre[tid] += add;
    __syncthreads();
  }
  const int m = spre[511];
  const int pref = spre[tid] - mylen;

  for (int j = 0; j < len0; ++j) {
    unsigned int p = stage[base0 + j];
    raw[pref + j] = p;
    atomicAdd(&cnt[p >> 17], 1);
  }
  for (int j = 0; j < len1; ++j) {
    unsigned int p = stage[base1 + j];
    raw[pref + len0 + j] = p;
    atomicAdd(&cnt[p >> 17], 1);
  }
  __syncthreads();

  int v = 0;
  if (tid < BNODES) { v = cnt[tid]; ts[tid] = v; }
  __syncthreads();
  for (int o = 1; o < BNODES; o <<= 1) {
    int add = (tid >= o && tid < BNODES) ? ts[tid - o] : 0;
    __syncthreads();
    if (tid < BNODES) ts[tid] += add;
    __syncthreads();
  }
  if (tid < BNODES) {
    int excl = ts[tid] - v;
    int node = n0 + tid;
    float dv = rsqrtf((float)v + 1.0f);
    dinvL[tid] = dv;
    if (node < N_NODES) {
      off[node]  = b * BCAP + excl;
      edeg[node] = v;
      dinv[node] = dv;
    }
    cnt[tid] = excl;
  }
  __syncthreads();

  for (int i = tid; i < m; i += 512) {
    unsigned int p = raw[i];
    int pos = atomicAdd(&cnt[p >> 17], 1);
    if (pos < BCAP) sorted[pos] = (int)(p & SRC_MASK);
  }
  __syncthreads();

  int* out = eSrc + (size_t)b * BCAP;
  for (int i = tid; i < m; i += 512) out[i] = sorted[i];

  const int rows = min(BNODES, N_NODES - n0);
  for (int i = tid; i < rows * 64; i += 512) {
    int r = i >> 6;
    size_t g = (size_t)(n0 + r) * 64 + (i & 63);
    Xs[g] = f2bf(dinvL[r] * x[g]);
  }
}

// ---------------------------------------------------------------------------
// CSR aggregation (v3, memory-floor bound): one wave per node, 8 edges per
// uint4 gather, bf16 out. FETCH ~160MB/layer at ~3.3 TB/s (measured R10-R12).
// ---------------------------------------------------------------------------
__global__ __launch_bounds__(256) void agg_csr(
    const int* __restrict__ off, const int* __restrict__ edeg,
    const int* __restrict__ eSrc, const unsigned short* __restrict__ Xs,
    const float* __restrict__ dinv, unsigned short* __restrict__ agg) {
  const int wid = (blockIdx.x * 256 + threadIdx.x) >> 6;
  const int lane = threadIdx.x & 63;
  const int grp = lane >> 3, sub = lane & 7;
  if (wid >= N_NODES) return;
  const int s0 = off[wid];
  const int s1 = s0 + edeg[wid];
  const uint4* XsV = (const uint4*)Xs;

  float2 acc[4];
  {
    uint4 u = XsV[(size_t)wid * 8 + sub];
    if (grp != 0) { u.x = 0; u.y = 0; u.z = 0; u.w = 0; }
    acc[0] = bfpair(u.x);
    acc[1] = bfpair(u.y);
    acc[2] = bfpair(u.z);
    acc[3] = bfpair(u.w);
  }

  int e = s0;
  const int eend = s1 - ((s1 - s0) & 31);
  for (; e < eend; e += 32) {
    int sa = eSrc[e + grp];
    int sb = eSrc[e + 8 + grp];
    int sc = eSrc[e + 16 + grp];
    int sd = eSrc[e + 24 + grp];
    uint4 ua = XsV[(size_t)sa * 8 + sub];
    uint4 ub = XsV[(size_t)sb * 8 + sub];
    uint4 uc = XsV[(size_t)sc * 8 + sub];
    uint4 ud = XsV[(size_t)sd * 8 + sub];
    addp(acc, ua); addp(acc, ub); addp(acc, uc); addp(acc, ud);
  }
  if (e < s1) {
    const int lim = s1 - 1;
    int ea = e + grp, eb = e + 8 + grp, ec = e + 16 + grp, ed = e + 24 + grp;
    int sa = eSrc[min(ea, lim)];
    int sb = eSrc[min(eb, lim)];
    int sc = eSrc[min(ec, lim)];
    int sd = eSrc[min(ed, lim)];
    uint4 ua = XsV[(size_t)sa * 8 + sub];
    uint4 ub = XsV[(size_t)sb * 8 + sub];
    uint4 uc = XsV[(size_t)sc * 8 + sub];
    uint4 ud = XsV[(size_t)sd * 8 + sub];
    if (ea > lim) { ua.x = 0; ua.y = 0; ua.z = 0; ua.w = 0; }
    if (eb > lim) { ub.x = 0; ub.y = 0; ub.z = 0; ub.w = 0; }
    if (ec > lim) { uc.x = 0; uc.y = 0; uc.z = 0; uc.w = 0; }
    if (ed > lim) { ud.x = 0; ud.y = 0; ud.z = 0; ud.w = 0; }
    addp(acc, ua); addp(acc, ub); addp(acc, uc); addp(acc, ud);
  }

  #pragma unroll
  for (int mk = 8; mk <= 32; mk <<= 1) {
    #pragma unroll
    for (int i = 0; i < 4; ++i) {
      acc[i].x += __shfl_xor(acc[i].x, mk, 64);
      acc[i].y += __shfl_xor(acc[i].y, mk, 64);
    }
  }

  if (grp == 0) {
    float dt = dinv[wid];
    uint4 o;
    o.x = ((unsigned)f2bf(acc[0].y * dt) << 16) | f2bf(acc[0].x * dt);
    o.y = ((unsigned)f2bf(acc[1].y * dt) << 16) | f2bf(acc[1].x * dt);
    o.z = ((unsigned)f2bf(acc[2].y * dt) << 16) | f2bf(acc[2].x * dt);
    o.w = ((unsigned)f2bf(acc[3].y * dt) << 16) | f2bf(acc[3].x * dt);
    *(uint4*)(agg + (size_t)wid * 64 + sub * 8) = o;
  }
}

// ---------------------------------------------------------------------------
// Fused MFMA GEMM + BN + activation (persistent grid, 782 co-resident blocks).
// Col stats padded ONE CACHELINE PER COLUMN: stats[j*16]=sum, stats[j*16+1]=sq
// (the R13 98us stall was ~100k fp32-atomic RMWs convoying on 4 cachelines).
//  mode 0: outb = bf16( dinv[row] * relu(y*a+c) )   (layer 1 -> Xs for layer 2)
//  mode 1: outf = fp32( relu(y*a+c) )               (layer 2 -> final output)
// ---------------------------------------------------------------------------
__global__ __launch_bounds__(256, 4) void gemm_fused(
    const unsigned short* __restrict__ A, const unsigned int* __restrict__ WcB,
    const float* __restrict__ bc, const float* __restrict__ g,
    const float* __restrict__ bt, const float* __restrict__ dinv,
    float* __restrict__ stats, int* __restrict__ ctr,
    unsigned short* __restrict__ outb, float* __restrict__ outf,
    const int mode) {
  const int tid = threadIdx.x;
  const int L = tid & 63, wv = tid >> 6;
  const int quad = L >> 4, l16 = L & 15;

  const bf16x8* Wv = (const bf16x8*)WcB;
  bf16x8 bfr[4][2];
  #pragma unroll
  for (int nt = 0; nt < 4; ++nt)
    #pragma unroll
    for (int kh = 0; kh < 2; ++kh)
      bfr[nt][kh] = Wv[(nt * 2 + kh) * 64 + L];
  float bcv[4];
  #pragma unroll
  for (int nt = 0; nt < 4; ++nt) bcv[nt] = bc[nt * 16 + l16];

  const bf16x8* Av = (const bf16x8*)A;
  float y[2][4][4];
  float psum[4] = {0.f, 0.f, 0.f, 0.f}, psq[4] = {0.f, 0.f, 0.f, 0.f};

  #pragma unroll
  for (int loop = 0; loop < 2; ++loop) {
    const int rowbase = blockIdx.x * 128 + loop * 64 + wv * 16;
    const int m = min(rowbase + l16, N_NODES - 1);
    bf16x8 a0 = Av[(size_t)m * 8 + quad];
    bf16x8 a1 = Av[(size_t)m * 8 + 4 + quad];
    #pragma unroll
    for (int nt = 0; nt < 4; ++nt) {
      f32x4 acc = {0.f, 0.f, 0.f, 0.f};
      acc = __builtin_amdgcn_mfma_f32_16x16x32_bf16(a0, bfr[nt][0], acc, 0, 0, 0);
      acc = __builtin_amdgcn_mfma_f32_16x16x32_bf16(a1, bfr[nt][1], acc, 0, 0, 0);
      #pragma unroll
      for (int r = 0; r < 4; ++r) {
        int row = rowbase + quad * 4 + r;
        float yy = acc[r] + bcv[nt];
        y[loop][nt][r] = yy;
        if (row < N_NODES) {
          psum[nt] += yy;
          psq[nt] += yy * yy;
        }
      }
    }
  }

  #pragma unroll
  for (int nt = 0; nt < 4; ++nt) {
    psum[nt] += __shfl_xor(psum[nt], 16, 64);
    psum[nt] += __shfl_xor(psum[nt], 32, 64);
    psq[nt]  += __shfl_xor(psq[nt], 16, 64);
    psq[nt]  += __shfl_xor(psq[nt], 32, 64);
  }
  __shared__ float rsum[4][64];
  __shared__ float rsq[4][64];
  if (L < 16) {
    #pragma unroll
    for (int nt = 0; nt < 4; ++nt) {
      rsum[wv][nt * 16 + L] = psum[nt];
      rsq[wv][nt * 16 + L]  = psq[nt];
    }
  }
  __syncthreads();
  if (tid < 64) {
    float s = rsum[0][tid] + rsum[1][tid] + rsum[2][tid] + rsum[3][tid];
    float q = rsq[0][tid] + rsq[1][tid] + rsq[2][tid] + rsq[3][tid];
    atomicAdd(&stats[tid * 16], s);       // one cacheline per column
    atomicAdd(&stats[tid * 16 + 1], q);
  }

  // ---- grid barrier (all 782 blocks co-resident by construction) ----
  __syncthreads();
  if (tid == 0) {
    __threadfence();
    atomicAdd(ctr, 1);
    while (__hip_atomic_load(ctr, __ATOMIC_RELAXED, __HIP_MEMORY_SCOPE_AGENT)
           < (int)gridDim.x)
      __builtin_amdgcn_s_sleep(32);
    __threadfence();
  }
  __syncthreads();

  // ---- phase B: finalize BN, transform the register tile, store once ----
  float av[4], cv[4];
  #pragma unroll
  for (int nt = 0; nt < 4; ++nt) {
    int j = nt * 16 + l16;
    float s = __hip_atomic_load(&stats[j * 16], __ATOMIC_RELAXED, __HIP_MEMORY_SCOPE_AGENT);
    float q = __hip_atomic_load(&stats[j * 16 + 1], __ATOMIC_RELAXED, __HIP_MEMORY_SCOPE_AGENT);
    float mu = s * (1.0f / N_NODES);
    float var = q * (1.0f / N_NODES) - mu * mu;
    float aa = rsqrtf(var + EPS) * g[j];
    av[nt] = aa;
    cv[nt] = bt[j] - mu * aa;
  }

  #pragma unroll
  for (int loop = 0; loop < 2; ++loop) {
    #pragma unroll
    for (int r = 0; r < 4; ++r) {
      int row = blockIdx.x * 128 + loop * 64 + wv * 16 + quad * 4 + r;
      if (row < N_NODES) {
        float dv = (mode == 0) ? dinv[row] : 1.0f;
        #pragma unroll
        for (int nt = 0; nt < 4; ++nt) {
          float t = fmaxf(fmaf(y[loop][nt][r], av[nt], cv[nt]), 0.f);
          int col = nt * 16 + l16;
          if (mode == 0)
            outb[(size_t)row * 64 + col] = f2bf(t * dv);
          else
            outf[(size_t)row * 64 + col] = t;
        }
      }
    }
  }
}

extern "C" void kernel_launch(void* const* d_in, const int* in_sizes, int n_in,
                              void* d_out, int out_size, void* d_ws, size_t ws_size,
                              hipStream_t stream) {
  const float* x   = (const float*)d_in[0];
  const int*   src = (const int*)d_in[1];          // edge_index row 0
  const int*   dst = src + N_EDGES;                // edge_index row 1
  const float* W1  = (const float*)d_in[2];
  const float* b1  = (const float*)d_in[3];
  const float* fw1 = (const float*)d_in[4];
  const float* fb1 = (const float*)d_in[5];
  const float* g1  = (const float*)d_in[6];
  const float* bt1 = (const float*)d_in[7];
  const float* W2  = (const float*)d_in[8];
  const float* b2  = (const float*)d_in[9];
  const float* fw2 = (const float*)d_in[10];
  const float* fb2 = (const float*)d_in[11];
  const float* g2  = (const float*)d_in[12];
  const float* bt2 = (const float*)d_in[13];

  float* out = (float*)d_out;                      // N x 64 fp32

  // workspace (~43 MB). stage aliases aggb; XsYb doubles as the bf16 Y buffer.
  unsigned char* w = (unsigned char*)d_ws;
  unsigned int*   stage = (unsigned int*)w;              // NB_P1*4096 uints
  unsigned short* aggb  = (unsigned short*)w;            // N*64 bf16 (alias)
  size_t ofs = ((size_t)NB_P1 * P1_CHUNK * 4 + 255) & ~(size_t)255;
  float*          dinv  = (float*)(w + ofs);             // N floats
  unsigned short* XsYb  = (unsigned short*)(dinv + N_NODES);          // N*64 bf16
  int*            eSrc  = (int*)(XsYb + (size_t)N_NODES * D);         // NBUCK*BCAP ints
  int*            off   = eSrc + (size_t)NBUCK * BCAP;   // N ints
  int*            edeg  = off + N_NODES;                 // N ints
  unsigned short* tbl   = (unsigned short*)(edeg + N_NODES);          // NB_P1*784 ushort
  unsigned int* WcB1 = (unsigned int*)(tbl + (size_t)NB_P1 * TBL_STRIDE); // 2048
  float* bc1  = (float*)(WcB1 + 2048);             // 64
  unsigned int* WcB2 = (unsigned int*)(bc1 + 64);  // 2048
  float* bc2  = (float*)(WcB2 + 2048);             // 64
  float* stats = bc2 + 64;                         // 2048 floats (64-line padded x2)
  float* stats1 = stats;                           // layer 1: [j*16]=sum, [j*16+1]=sq
  float* stats2 = stats + 1024;                    // layer 2
  int*   ctr  = (int*)(stats + 2048);              // 2 barrier counters

  const int nd = N_NODES * D;
  dim3 blk(256);

  // 1. partition chunks + weight fold (2 extra blocks ride along)
  pass1_sort<<<NB_P1 + 2, blk, 0, stream>>>(src, dst, stage, tbl,
                                            W1, b1, fw1, fb1, W2, b2, fw2, fb2,
                                            WcB1, bc1, WcB2, bc2);
  // 2. bucket CSR build + L1 prescale + zero stats/ctr (block 0)
  pass2_sort<<<NBUCK, 512, 0, stream>>>(stage, tbl, eSrc, off, edeg, dinv, x,
                                        XsYb, stats, ctr);
  // 3-4. layer 1
  agg_csr<<<(nd + 255) / 256, blk, 0, stream>>>(off, edeg, eSrc, XsYb, dinv, aggb);
  gemm_fused<<<NGB, blk, 0, stream>>>(aggb, WcB1, bc1, g1, bt1, dinv,
                                      stats1, &ctr[0], XsYb, out, 0);
  // 5-6. layer 2
  agg_csr<<<(nd + 255) / 256, blk, 0, stream>>>(off, edeg, eSrc, XsYb, dinv, aggb);
  gemm_fused<<<NGB, blk, 0, stream>>>(aggb, WcB2, bc2, g2, bt2, dinv,
                                      stats2, &ctr[1], XsYb, out, 1);
}

// Round 15
// 382.848 us; speedup vs baseline: 1.2158x; 1.2158x over previous
//
#include <hip/hip_runtime.h>

#define N_NODES 100000
#define N_EDGES 3200000
#define D 64
#define EPS 1e-5f

#define BSHIFT 7
#define BNODES 128                                          // nodes per bucket
#define NBUCK ((N_NODES + BNODES - 1) / BNODES)             // 782
#define P1_CHUNK 4096
#define NB_P1 ((N_EDGES + P1_CHUNK - 1) / P1_CHUNK)         // 782
#define SRC_MASK 0x1FFFFu                                   // 17 bits >= 100000
#define BCAP 4480                                           // bucket region cap
#define TBL_STRIDE 784                                      // 783 entries + pad

typedef __attribute__((ext_vector_type(8))) short bf16x8;   // 8 bf16 = 4 VGPRs
typedef __attribute__((ext_vector_type(4))) float f32x4;

__device__ __forceinline__ unsigned short f2bf(float f) {
  unsigned int u = __float_as_uint(f);
  u += 0x7FFFu + ((u >> 16) & 1u);          // round to nearest even
  return (unsigned short)(u >> 16);
}
__device__ __forceinline__ float bf2f(unsigned short h) {
  return __uint_as_float(((unsigned int)h) << 16);
}
__device__ __forceinline__ float2 bfpair(unsigned int u) {
  return make_float2(__uint_as_float(u << 16), __uint_as_float(u & 0xFFFF0000u));
}
__device__ __forceinline__ void addp(float2 a[4], uint4 u) {
  a[0] += bfpair(u.x);
  a[1] += bfpair(u.y);
  a[2] += bfpair(u.z);
  a[3] += bfpair(u.w);
}

// ---------------------------------------------------------------------------
// Pass 1 (+ weight fold): blocks [0, NB_P1) partition a 4096-edge chunk by
// 128-node bucket (block-local counting sort, coalesced out). Blocks
// NB_P1+{0,1} fold GCNConv+FC weights of layer 1/2 into MFMA-B-swizzled bf16.
// ---------------------------------------------------------------------------
__global__ __launch_bounds__(256) void pass1_sort(
    const int* __restrict__ src, const int* __restrict__ dst,
    unsigned int* __restrict__ stage, unsigned short* __restrict__ tbl,
    const float* __restrict__ W1, const float* __restrict__ b1,
    const float* __restrict__ fw1, const float* __restrict__ fb1,
    const float* __restrict__ W2, const float* __restrict__ b2,
    const float* __restrict__ fw2, const float* __restrict__ fb2,
    unsigned int* __restrict__ WcB1, float* __restrict__ bc1,
    unsigned int* __restrict__ WcB2, float* __restrict__ bc2) {
  __shared__ union {
    struct { unsigned int hist[NBUCK]; unsigned int ts[256]; unsigned int sorted[P1_CHUNK]; } p;
    struct { float sW[4096]; float sfT[65 * 64]; } c;   // sfT padded: col reads bank-clean
  } sm;
  const int tid = threadIdx.x;

  if (blockIdx.x >= NB_P1) {                 // ---- weight-fold path ----
    const int layer = blockIdx.x - NB_P1;
    const float* W  = layer ? W2  : W1;
    const float* fw = layer ? fw2 : fw1;
    const float* b  = layer ? b2  : b1;
    const float* fb = layer ? fb2 : fb1;
    unsigned int* WcB = layer ? WcB2 : WcB1;
    float* bc = layer ? bc2 : bc1;

    for (int i = tid; i < 4096; i += 256) {
      sm.c.sW[i] = W[i];
      int t = i >> 6, n = i & 63;
      sm.c.sfT[n * 65 + t] = fw[i];          // transposed+padded
    }
    __syncthreads();
    // Wc = W @ fw emitted in B-fragment swizzle (bf16 pairs):
    // uint o: jj=o&3, L=(o>>2)&63, kh=(o>>8)&1, nt=o>>9;
    // k0=(L>>4)*8+jj*2+kh*32, n=nt*16+(L&15); packs C[k0][n], C[k0+1][n].
    for (int o = tid; o < 2048; o += 256) {
      int jj = o & 3, L = (o >> 2) & 63, kh = (o >> 8) & 1, nt = o >> 9;
      int k0 = (L >> 4) * 8 + jj * 2 + kh * 32;
      int n  = nt * 16 + (L & 15);
      float d0 = 0.f, d1 = 0.f;
      #pragma unroll
      for (int t = 0; t < 64; ++t) {
        float f = sm.c.sfT[n * 65 + t];
        d0 += sm.c.sW[k0 * 64 + t] * f;
        d1 += sm.c.sW[(k0 + 1) * 64 + t] * f;
      }
      WcB[o] = ((unsigned)f2bf(d1) << 16) | f2bf(d0);
    }
    if (tid < 64) {
      float acc = fb[tid];
      #pragma unroll
      for (int k = 0; k < 64; ++k) acc += b[k] * sm.c.sfT[tid * 65 + k];
      bc[tid] = acc;
    }
    return;
  }

  // ---- partition path ----
  const int e0 = blockIdx.x * P1_CHUNK;
  for (int b = tid; b < NBUCK; b += 256) sm.p.hist[b] = 0;
  __syncthreads();

  int dreg[16];
  #pragma unroll
  for (int k = 0; k < 16; ++k) {
    int e = e0 + k * 256 + tid;
    int d = (e < N_EDGES) ? dst[e] : -1;
    dreg[k] = d;
    if (d >= 0) atomicAdd(&sm.p.hist[((unsigned)d) >> BSHIFT], 1u);
  }
  __syncthreads();

  unsigned int v[4], run = 0;
  #pragma unroll
  for (int j = 0; j < 4; ++j) {
    int bk = 4 * tid + j;
    unsigned int h = (bk < NBUCK) ? sm.p.hist[bk] : 0u;
    v[j] = run;
    run += h;
  }
  sm.p.ts[tid] = run;
  __syncthreads();
  for (int o = 1; o < 256; o <<= 1) {
    unsigned int add = (tid >= o) ? sm.p.ts[tid - o] : 0u;
    __syncthreads();
    sm.p.ts[tid] += add;
    __syncthreads();
  }
  const unsigned int excl = sm.p.ts[tid] - run;
  const unsigned int m = sm.p.ts[255];
  unsigned short* trow = tbl + (size_t)blockIdx.x * TBL_STRIDE;
  #pragma unroll
  for (int j = 0; j < 4; ++j) {
    int bk = 4 * tid + j;
    if (bk < NBUCK) {
      unsigned int o = excl + v[j];
      sm.p.hist[bk] = o;
      trow[bk] = (unsigned short)o;
    }
  }
  if (tid == 0) trow[NBUCK] = (unsigned short)m;
  __syncthreads();

  #pragma unroll
  for (int k = 0; k < 16; ++k) {
    int e = e0 + k * 256 + tid;
    int t = dreg[k];
    if (t >= 0) {
      unsigned int pos = atomicAdd(&sm.p.hist[((unsigned)t) >> BSHIFT], 1u);
      sm.p.sorted[pos] = (((unsigned)(t & (BNODES - 1))) << 17) | (unsigned)src[e];
    }
  }
  __syncthreads();

  unsigned int* so = stage + (size_t)blockIdx.x * P1_CHUNK;
  for (int i = tid; i < (int)m; i += 256) so[i] = sm.p.sorted[i];
}

// ---------------------------------------------------------------------------
// Pass 2: paired-segment gather -> LDS counting sort to node CSR + fused
// layer-1 prescale. Block 0 zeroes the line-padded stats[2048].
// ---------------------------------------------------------------------------
__global__ __launch_bounds__(512) void pass2_sort(
    const unsigned int* __restrict__ stage, const unsigned short* __restrict__ tbl,
    int* __restrict__ eSrc, int* __restrict__ off, int* __restrict__ edeg,
    float* __restrict__ dinv, const float* __restrict__ x,
    unsigned short* __restrict__ Xs, float* __restrict__ statsZ) {
  __shared__ int spre[512];
  __shared__ int cnt[BNODES];
  __shared__ int ts[BNODES];
  __shared__ float dinvL[BNODES];
  __shared__ unsigned int raw[BCAP];
  __shared__ int sorted[BCAP];
  const int b = blockIdx.x, tid = threadIdx.x;
  const int n0 = b * BNODES;

  if (b == 0) {
    #pragma unroll
    for (int k = 0; k < 4; ++k) statsZ[tid * 4 + k] = 0.0f;  // 2048 floats
  }

  int base0 = 0, base1 = 0, len0 = 0, len1 = 0;
  {
    int s0 = 2 * tid, s1 = 2 * tid + 1;
    if (s0 < NB_P1) {
      const unsigned short* trow = tbl + (size_t)s0 * TBL_STRIDE;
      int o0 = trow[b], o1 = trow[b + 1];
      base0 = s0 * P1_CHUNK + o0;
      len0 = o1 - o0;
    }
    if (s1 < NB_P1) {
      const unsigned short* trow = tbl + (size_t)s1 * TBL_STRIDE;
      int o0 = trow[b], o1 = trow[b + 1];
      base1 = s1 * P1_CHUNK + o0;
      len1 = o1 - o0;
    }
  }
  if (tid < BNODES) cnt[tid] = 0;
  const int mylen = len0 + len1;
  spre[tid] = mylen;
  __syncthreads();
  for (int o = 1; o < 512; o <<= 1) {
    int add = (tid >= o) ? spre[tid - o] : 0;
    __syncthreads();
    spre[tid] += add;
    __syncthreads();
  }
  const int m = spre[511];
  const int pref = spre[tid] - mylen;

  for (int j = 0; j < len0; ++j) {
    unsigned int p = stage[base0 + j];
    raw[pref + j] = p;
    atomicAdd(&cnt[p >> 17], 1);
  }
  for (int j = 0; j < len1; ++j) {
    unsigned int p = stage[base1 + j];
    raw[pref + len0 + j] = p;
    atomicAdd(&cnt[p >> 17], 1);
  }
  __syncthreads();

  int v = 0;
  if (tid < BNODES) { v = cnt[tid]; ts[tid] = v; }
  __syncthreads();
  for (int o = 1; o < BNODES; o <<= 1) {
    int add = (tid >= o && tid < BNODES) ? ts[tid - o] : 0;
    __syncthreads();
    if (tid < BNODES) ts[tid] += add;
    __syncthreads();
  }
  if (tid < BNODES) {
    int excl = ts[tid] - v;
    int node = n0 + tid;
    float dv = rsqrtf((float)v + 1.0f);
    dinvL[tid] = dv;
    if (node < N_NODES) {
      off[node]  = b * BCAP + excl;
      edeg[node] = v;
      dinv[node] = dv;
    }
    cnt[tid] = excl;
  }
  __syncthreads();

  for (int i = tid; i < m; i += 512) {
    unsigned int p = raw[i];
    int pos = atomicAdd(&cnt[p >> 17], 1);
    if (pos < BCAP) sorted[pos] = (int)(p & SRC_MASK);
  }
  __syncthreads();

  int* out = eSrc + (size_t)b * BCAP;
  for (int i = tid; i < m; i += 512) out[i] = sorted[i];

  const int rows = min(BNODES, N_NODES - n0);
  for (int i = tid; i < rows * 64; i += 512) {
    int r = i >> 6;
    size_t g = (size_t)(n0 + r) * 64 + (i & 63);
    Xs[g] = f2bf(dinvL[r] * x[g]);
  }
}

// ---------------------------------------------------------------------------
// CSR aggregation (v3, memory-floor bound): one wave per node, 8 edges per
// uint4 gather, bf16 out. FETCH ~160MB/layer at ~3.3 TB/s (measured R10-R12).
// ---------------------------------------------------------------------------
__global__ __launch_bounds__(256) void agg_csr(
    const int* __restrict__ off, const int* __restrict__ edeg,
    const int* __restrict__ eSrc, const unsigned short* __restrict__ Xs,
    const float* __restrict__ dinv, unsigned short* __restrict__ agg) {
  const int wid = (blockIdx.x * 256 + threadIdx.x) >> 6;
  const int lane = threadIdx.x & 63;
  const int grp = lane >> 3, sub = lane & 7;
  if (wid >= N_NODES) return;
  const int s0 = off[wid];
  const int s1 = s0 + edeg[wid];
  const uint4* XsV = (const uint4*)Xs;

  float2 acc[4];
  {
    uint4 u = XsV[(size_t)wid * 8 + sub];
    if (grp != 0) { u.x = 0; u.y = 0; u.z = 0; u.w = 0; }
    acc[0] = bfpair(u.x);
    acc[1] = bfpair(u.y);
    acc[2] = bfpair(u.z);
    acc[3] = bfpair(u.w);
  }

  int e = s0;
  const int eend = s1 - ((s1 - s0) & 31);
  for (; e < eend; e += 32) {
    int sa = eSrc[e + grp];
    int sb = eSrc[e + 8 + grp];
    int sc = eSrc[e + 16 + grp];
    int sd = eSrc[e + 24 + grp];
    uint4 ua = XsV[(size_t)sa * 8 + sub];
    uint4 ub = XsV[(size_t)sb * 8 + sub];
    uint4 uc = XsV[(size_t)sc * 8 + sub];
    uint4 ud = XsV[(size_t)sd * 8 + sub];
    addp(acc, ua); addp(acc, ub); addp(acc, uc); addp(acc, ud);
  }
  if (e < s1) {
    const int lim = s1 - 1;
    int ea = e + grp, eb = e + 8 + grp, ec = e + 16 + grp, ed = e + 24 + grp;
    int sa = eSrc[min(ea, lim)];
    int sb = eSrc[min(eb, lim)];
    int sc = eSrc[min(ec, lim)];
    int sd = eSrc[min(ed, lim)];
    uint4 ua = XsV[(size_t)sa * 8 + sub];
    uint4 ub = XsV[(size_t)sb * 8 + sub];
    uint4 uc = XsV[(size_t)sc * 8 + sub];
    uint4 ud = XsV[(size_t)sd * 8 + sub];
    if (ea > lim) { ua.x = 0; ua.y = 0; ua.z = 0; ua.w = 0; }
    if (eb > lim) { ub.x = 0; ub.y = 0; ub.z = 0; ub.w = 0; }
    if (ec > lim) { uc.x = 0; uc.y = 0; uc.z = 0; uc.w = 0; }
    if (ed > lim) { ud.x = 0; ud.y = 0; ud.z = 0; ud.w = 0; }
    addp(acc, ua); addp(acc, ub); addp(acc, uc); addp(acc, ud);
  }

  #pragma unroll
  for (int mk = 8; mk <= 32; mk <<= 1) {
    #pragma unroll
    for (int i = 0; i < 4; ++i) {
      acc[i].x += __shfl_xor(acc[i].x, mk, 64);
      acc[i].y += __shfl_xor(acc[i].y, mk, 64);
    }
  }

  if (grp == 0) {
    float dt = dinv[wid];
    uint4 o;
    o.x = ((unsigned)f2bf(acc[0].y * dt) << 16) | f2bf(acc[0].x * dt);
    o.y = ((unsigned)f2bf(acc[1].y * dt) << 16) | f2bf(acc[1].x * dt);
    o.z = ((unsigned)f2bf(acc[2].y * dt) << 16) | f2bf(acc[2].x * dt);
    o.w = ((unsigned)f2bf(acc[3].y * dt) << 16) | f2bf(acc[3].x * dt);
    *(uint4*)(agg + (size_t)wid * 64 + sub * 8) = o;
  }
}

// ---------------------------------------------------------------------------
// MFMA GEMM: Yb(bf16)[128-row block] = A(bf16) @ WcB + bc, fused col stats.
// Stats line-padded: stats[j*16]=sum_j, stats[j*16+1]=sq_j (64 lines, not 4).
// ---------------------------------------------------------------------------
__global__ __launch_bounds__(256) void gemm_stats(
    const unsigned short* __restrict__ A, const unsigned int* __restrict__ WcB,
    const float* __restrict__ bc, unsigned short* __restrict__ Yb,
    float* __restrict__ stats) {
  const int tid = threadIdx.x;
  const int L = tid & 63, wv = tid >> 6;
  const int quad = L >> 4, l16 = L & 15;

  const bf16x8* Wv = (const bf16x8*)WcB;
  bf16x8 bfr[4][2];
  #pragma unroll
  for (int nt = 0; nt < 4; ++nt)
    #pragma unroll
    for (int kh = 0; kh < 2; ++kh)
      bfr[nt][kh] = Wv[(nt * 2 + kh) * 64 + L];
  float bcv[4];
  #pragma unroll
  for (int nt = 0; nt < 4; ++nt) bcv[nt] = bc[nt * 16 + l16];

  const bf16x8* Av = (const bf16x8*)A;
  float psum[4] = {0.f, 0.f, 0.f, 0.f}, psq[4] = {0.f, 0.f, 0.f, 0.f};

  #pragma unroll
  for (int loop = 0; loop < 2; ++loop) {
    const int rowbase = blockIdx.x * 128 + loop * 64 + wv * 16;
    const int m = min(rowbase + l16, N_NODES - 1);
    bf16x8 a0 = Av[(size_t)m * 8 + quad];
    bf16x8 a1 = Av[(size_t)m * 8 + 4 + quad];
    #pragma unroll
    for (int nt = 0; nt < 4; ++nt) {
      f32x4 acc = {0.f, 0.f, 0.f, 0.f};
      acc = __builtin_amdgcn_mfma_f32_16x16x32_bf16(a0, bfr[nt][0], acc, 0, 0, 0);
      acc = __builtin_amdgcn_mfma_f32_16x16x32_bf16(a1, bfr[nt][1], acc, 0, 0, 0);
      #pragma unroll
      for (int r = 0; r < 4; ++r) {
        int row = rowbase + quad * 4 + r;
        if (row < N_NODES) {
          float y = acc[r] + bcv[nt];
          Yb[(size_t)row * 64 + nt * 16 + l16] = f2bf(y);
          psum[nt] += y;
          psq[nt] += y * y;
        }
      }
    }
  }

  #pragma unroll
  for (int nt = 0; nt < 4; ++nt) {
    psum[nt] += __shfl_xor(psum[nt], 16, 64);
    psum[nt] += __shfl_xor(psum[nt], 32, 64);
    psq[nt]  += __shfl_xor(psq[nt], 16, 64);
    psq[nt]  += __shfl_xor(psq[nt], 32, 64);
  }
  __shared__ float rsum[4][64];
  __shared__ float rsq[4][64];
  if (L < 16) {
    #pragma unroll
    for (int nt = 0; nt < 4; ++nt) {
      rsum[wv][nt * 16 + L] = psum[nt];
      rsq[wv][nt * 16 + L]  = psq[nt];
    }
  }
  __syncthreads();
  if (tid < 64) {
    float s = rsum[0][tid] + rsum[1][tid] + rsum[2][tid] + rsum[3][tid];
    float q = rsq[0][tid] + rsq[1][tid] + rsq[2][tid] + rsq[3][tid];
    atomicAdd(&stats[tid * 16], s);       // one cacheline per column
    atomicAdd(&stats[tid * 16 + 1], q);
  }
}

// ---------------------------------------------------------------------------
// prescale_y (+inline finalize of layer-1 BN), in place over the Yb buffer
// ---------------------------------------------------------------------------
__global__ __launch_bounds__(256) void prescale_y(
    unsigned short* __restrict__ YbXs, const float* __restrict__ dinv,
    const float* __restrict__ stats, const float* __restrict__ g,
    const float* __restrict__ bt) {
  __shared__ float sa[64], sc[64];
  if (threadIdx.x < 64) {
    int j = threadIdx.x;
    float mu = stats[j * 16] * (1.0f / N_NODES);
    float var = stats[j * 16 + 1] * (1.0f / N_NODES) - mu * mu;
    float s = rsqrtf(var + EPS) * g[j];
    sa[j] = s;
    sc[j] = bt[j] - mu * s;
  }
  __syncthreads();
  int idx = blockIdx.x * blockDim.x + threadIdx.x;
  if (idx < N_NODES * D) {
    int i = idx >> 6, j = idx & 63;
    float y = bf2f(YbXs[idx]);
    YbXs[idx] = f2bf(dinv[i] * fmaxf(fmaf(y, sa[j], sc[j]), 0.f));
  }
}

// ---------------------------------------------------------------------------
// final_norm (+inline finalize of layer-2 BN): out = relu(Yb*a2 + c2), fp32
// ---------------------------------------------------------------------------
__global__ __launch_bounds__(256) void final_norm(
    const unsigned short* __restrict__ Yb, float* __restrict__ out,
    const float* __restrict__ stats, const float* __restrict__ g,
    const float* __restrict__ bt) {
  __shared__ float sa[64], sc[64];
  if (threadIdx.x < 64) {
    int j = threadIdx.x;
    float mu = stats[j * 16] * (1.0f / N_NODES);
    float var = stats[j * 16 + 1] * (1.0f / N_NODES) - mu * mu;
    float s = rsqrtf(var + EPS) * g[j];
    sa[j] = s;
    sc[j] = bt[j] - mu * s;
  }
  __syncthreads();
  int idx = blockIdx.x * blockDim.x + threadIdx.x;
  if (idx < N_NODES * D) {
    int j = idx & 63;
    out[idx] = fmaxf(fmaf(bf2f(Yb[idx]), sa[j], sc[j]), 0.f);
  }
}

extern "C" void kernel_launch(void* const* d_in, const int* in_sizes, int n_in,
                              void* d_out, int out_size, void* d_ws, size_t ws_size,
                              hipStream_t stream) {
  const float* x   = (const float*)d_in[0];
  const int*   src = (const int*)d_in[1];          // edge_index row 0
  const int*   dst = src + N_EDGES;                // edge_index row 1
  const float* W1  = (const float*)d_in[2];
  const float* b1  = (const float*)d_in[3];
  const float* fw1 = (const float*)d_in[4];
  const float* fb1 = (const float*)d_in[5];
  const float* g1  = (const float*)d_in[6];
  const float* bt1 = (const float*)d_in[7];
  const float* W2  = (const float*)d_in[8];
  const float* b2  = (const float*)d_in[9];
  const float* fw2 = (const float*)d_in[10];
  const float* fb2 = (const float*)d_in[11];
  const float* g2  = (const float*)d_in[12];
  const float* bt2 = (const float*)d_in[13];

  float* out = (float*)d_out;                      // N x 64 fp32

  // workspace (~43 MB). stage aliases aggb; XsYb doubles as the bf16 Y buffer.
  unsigned char* w = (unsigned char*)d_ws;
  unsigned int*   stage = (unsigned int*)w;              // NB_P1*4096 uints
  unsigned short* aggb  = (unsigned short*)w;            // N*64 bf16 (alias)
  size_t ofs = ((size_t)NB_P1 * P1_CHUNK * 4 + 255) & ~(size_t)255;
  float*          dinv  = (float*)(w + ofs);             // N floats
  unsigned short* XsYb  = (unsigned short*)(dinv + N_NODES);          // N*64 bf16
  int*            eSrc  = (int*)(XsYb + (size_t)N_NODES * D);         // NBUCK*BCAP ints
  int*            off   = eSrc + (size_t)NBUCK * BCAP;   // N ints
  int*            edeg  = off + N_NODES;                 // N ints
  unsigned short* tbl   = (unsigned short*)(edeg + N_NODES);          // NB_P1*784 ushort
  unsigned int* WcB1 = (unsigned int*)(tbl + (size_t)NB_P1 * TBL_STRIDE); // 2048
  float* bc1  = (float*)(WcB1 + 2048);             // 64
  unsigned int* WcB2 = (unsigned int*)(bc1 + 64);  // 2048
  float* bc2  = (float*)(WcB2 + 2048);             // 64
  float* stats  = bc2 + 64;                        // 2048 floats, line-padded
  float* stats1 = stats;                           // layer 1: [j*16]=sum,[j*16+1]=sq
  float* stats2 = stats + 1024;                    // layer 2

  const int nd = N_NODES * D;
  dim3 blk(256);

  // 1. partition chunks + weight fold (2 rider blocks)
  pass1_sort<<<NB_P1 + 2, blk, 0, stream>>>(src, dst, stage, tbl,
                                            W1, b1, fw1, fb1, W2, b2, fw2, fb2,
                                            WcB1, bc1, WcB2, bc2);
  // 2. bucket CSR build + L1 prescale + zero stats (block 0)
  pass2_sort<<<NBUCK, 512, 0, stream>>>(stage, tbl, eSrc, off, edeg, dinv, x,
                                        XsYb, stats);
  // 3-5. layer 1
  agg_csr<<<(nd + 255) / 256, blk, 0, stream>>>(off, edeg, eSrc, XsYb, dinv, aggb);
  gemm_stats<<<(N_NODES + 127) / 128, blk, 0, stream>>>(aggb, WcB1, bc1, XsYb, stats1);
  prescale_y<<<(nd + 255) / 256, blk, 0, stream>>>(XsYb, dinv, stats1, g1, bt1);
  // 6-8. layer 2
  agg_csr<<<(nd + 255) / 256, blk, 0, stream>>>(off, edeg, eSrc, XsYb, dinv, aggb);
  gemm_stats<<<(N_NODES + 127) / 128, blk, 0, stream>>>(aggb, WcB2, bc2, XsYb, stats2);
  final_norm<<<(nd + 255) / 256, blk, 0, stream>>>(XsYb, out, stats2, g2, bt2);
}

// Round 16
// 382.384 us; speedup vs baseline: 1.2172x; 1.0012x over previous
//
#include <hip/hip_runtime.h>

#define N_NODES 100000
#define N_EDGES 3200000
#define D 64
#define EPS 1e-5f

#define BSHIFT 7
#define BNODES 128                                          // nodes per bucket
#define NBUCK ((N_NODES + BNODES - 1) / BNODES)             // 782
#define P1_CHUNK 4096
#define NB_P1 ((N_EDGES + P1_CHUNK - 1) / P1_CHUNK)         // 782
#define SRC_MASK 0x1FFFFu                                   // 17 bits >= 100000
#define BCAP 4480                                           // bucket region cap
#define TBL_STRIDE 784                                      // 783 entries + pad

typedef __attribute__((ext_vector_type(8))) short bf16x8;   // 8 bf16 = 4 VGPRs
typedef __attribute__((ext_vector_type(4))) float f32x4;

__device__ __forceinline__ unsigned short f2bf(float f) {
  unsigned int u = __float_as_uint(f);
  u += 0x7FFFu + ((u >> 16) & 1u);          // round to nearest even
  return (unsigned short)(u >> 16);
}
__device__ __forceinline__ float bf2f(unsigned short h) {
  return __uint_as_float(((unsigned int)h) << 16);
}
__device__ __forceinline__ float2 bfpair(unsigned int u) {
  return make_float2(__uint_as_float(u << 16), __uint_as_float(u & 0xFFFF0000u));
}
__device__ __forceinline__ void addp(float2 a[4], uint4 u) {
  a[0] += bfpair(u.x);
  a[1] += bfpair(u.y);
  a[2] += bfpair(u.z);
  a[3] += bfpair(u.w);
}

// ---------------------------------------------------------------------------
// blocks 0,1: fold GCNConv+FC into 64x64, emit MFMA-B-swizzled bf16 + bc.
// block 2: zero the line-padded BN stat region (2048 floats).
// ---------------------------------------------------------------------------
__global__ __launch_bounds__(256) void combine_weights(
    const float* __restrict__ W1, const float* __restrict__ b1,
    const float* __restrict__ fw1, const float* __restrict__ fb1,
    const float* __restrict__ W2, const float* __restrict__ b2,
    const float* __restrict__ fw2, const float* __restrict__ fb2,
    unsigned int* __restrict__ WcB1, float* __restrict__ bc1,
    unsigned int* __restrict__ WcB2, float* __restrict__ bc2,
    float* __restrict__ stats) {
  if (blockIdx.x == 2) {
    #pragma unroll
    for (int k = 0; k < 8; ++k) stats[threadIdx.x * 8 + k] = 0.0f;  // 2048
    return;
  }
  const float* W  = blockIdx.x ? W2  : W1;
  const float* fw = blockIdx.x ? fw2 : fw1;
  const float* b  = blockIdx.x ? b2  : b1;
  const float* fb = blockIdx.x ? fb2 : fb1;
  unsigned int* WcB = blockIdx.x ? WcB2 : WcB1;
  float* bc = blockIdx.x ? bc2 : bc1;

  __shared__ float sW[64 * 64];
  __shared__ float sf[64 * 64];
  __shared__ float sC[64 * 64];
  for (int i = threadIdx.x; i < 4096; i += 256) { sW[i] = W[i]; sf[i] = fw[i]; }
  __syncthreads();
  for (int o = threadIdx.x; o < 4096; o += 256) {
    int i = o >> 6, j = o & 63;
    float acc = 0.f;
    #pragma unroll
    for (int k = 0; k < 64; ++k) acc += sW[i * 64 + k] * sf[k * 64 + j];
    sC[o] = acc;
  }
  __syncthreads();
  // B-fragment swizzle: frag f=(nt*2+kh), lane L, elem j -> B[(L>>4)*8+j+kh*32][nt*16+(L&15)]
  for (int o = threadIdx.x; o < 2048; o += 256) {
    int jj = o & 3, L = (o >> 2) & 63, kh = (o >> 8) & 1, nt = o >> 9;
    int k0 = (L >> 4) * 8 + jj * 2 + kh * 32;
    int n  = nt * 16 + (L & 15);
    unsigned int lo = f2bf(sC[k0 * 64 + n]);
    unsigned int hi = f2bf(sC[(k0 + 1) * 64 + n]);
    WcB[o] = (hi << 16) | lo;
  }
  if (threadIdx.x < 64) {
    int j = threadIdx.x;
    float acc = fb[j];
    #pragma unroll
    for (int k = 0; k < 64; ++k) acc += b[k] * sf[k * 64 + j];
    bc[j] = acc;
  }
}

// ---------------------------------------------------------------------------
// Pass 1: block-local counting sort of a 4096-edge chunk by 128-node bucket.
// 782 blocks x 256 threads, lean 20.5 KB LDS (~7 resident blocks/CU).
// ---------------------------------------------------------------------------
__global__ __launch_bounds__(256) void pass1_sort(
    const int* __restrict__ src, const int* __restrict__ dst,
    unsigned int* __restrict__ stage, unsigned short* __restrict__ tbl) {
  __shared__ unsigned int hist[NBUCK];
  __shared__ unsigned int ts[256];
  __shared__ unsigned int sorted[P1_CHUNK];
  const int tid = threadIdx.x;
  const int e0 = blockIdx.x * P1_CHUNK;

  for (int b = tid; b < NBUCK; b += 256) hist[b] = 0;
  __syncthreads();

  int dreg[16];                               // dst cached -> no second dst read
  #pragma unroll
  for (int k = 0; k < 16; ++k) {
    int e = e0 + k * 256 + tid;
    int d = (e < N_EDGES) ? dst[e] : -1;
    dreg[k] = d;
    if (d >= 0) atomicAdd(&hist[((unsigned)d) >> BSHIFT], 1u);
  }
  __syncthreads();

  unsigned int v[4], run = 0;
  #pragma unroll
  for (int j = 0; j < 4; ++j) {
    int bk = 4 * tid + j;
    unsigned int h = (bk < NBUCK) ? hist[bk] : 0u;
    v[j] = run;
    run += h;
  }
  ts[tid] = run;
  __syncthreads();
  for (int o = 1; o < 256; o <<= 1) {
    unsigned int add = (tid >= o) ? ts[tid - o] : 0u;
    __syncthreads();
    ts[tid] += add;
    __syncthreads();
  }
  const unsigned int excl = ts[tid] - run;
  const unsigned int m = ts[255];
  unsigned short* trow = tbl + (size_t)blockIdx.x * TBL_STRIDE;
  #pragma unroll
  for (int j = 0; j < 4; ++j) {
    int bk = 4 * tid + j;
    if (bk < NBUCK) {
      unsigned int o = excl + v[j];
      hist[bk] = o;
      trow[bk] = (unsigned short)o;
    }
  }
  if (tid == 0) trow[NBUCK] = (unsigned short)m;
  __syncthreads();

  #pragma unroll
  for (int k = 0; k < 16; ++k) {
    int e = e0 + k * 256 + tid;
    int t = dreg[k];
    if (t >= 0) {
      unsigned int pos = atomicAdd(&hist[((unsigned)t) >> BSHIFT], 1u);
      sorted[pos] = (((unsigned)(t & (BNODES - 1))) << 17) | (unsigned)src[e];
    }
  }
  __syncthreads();

  unsigned int* so = stage + (size_t)blockIdx.x * P1_CHUNK;
  for (int i = tid; i < (int)m; i += 256) so[i] = sorted[i];
}

// ---------------------------------------------------------------------------
// Pass 2: paired-segment gather (thread owns chunk-segments 2t, 2t+1), single
// read of stage, LDS counting sort to node CSR. Emits eSrc, off, edeg, dinv,
// and the fused layer-1 prescale Xs.
// ---------------------------------------------------------------------------
__global__ __launch_bounds__(512) void pass2_sort(
    const unsigned int* __restrict__ stage, const unsigned short* __restrict__ tbl,
    int* __restrict__ eSrc, int* __restrict__ off, int* __restrict__ edeg,
    float* __restrict__ dinv, const float* __restrict__ x,
    unsigned short* __restrict__ Xs) {
  __shared__ int spre[512];
  __shared__ int cnt[BNODES];
  __shared__ int ts[BNODES];
  __shared__ float dinvL[BNODES];
  __shared__ unsigned int raw[BCAP];
  __shared__ int sorted[BCAP];
  const int b = blockIdx.x, tid = threadIdx.x;
  const int n0 = b * BNODES;

  int base0 = 0, base1 = 0, len0 = 0, len1 = 0;
  {
    int s0 = 2 * tid, s1 = 2 * tid + 1;
    if (s0 < NB_P1) {
      const unsigned short* trow = tbl + (size_t)s0 * TBL_STRIDE;
      int o0 = trow[b], o1 = trow[b + 1];
      base0 = s0 * P1_CHUNK + o0;
      len0 = o1 - o0;
    }
    if (s1 < NB_P1) {
      const unsigned short* trow = tbl + (size_t)s1 * TBL_STRIDE;
      int o0 = trow[b], o1 = trow[b + 1];
      base1 = s1 * P1_CHUNK + o0;
      len1 = o1 - o0;
    }
  }
  if (tid < BNODES) cnt[tid] = 0;
  const int mylen = len0 + len1;
  spre[tid] = mylen;
  __syncthreads();
  for (int o = 1; o < 512; o <<= 1) {
    int add = (tid >= o) ? spre[tid - o] : 0;
    __syncthreads();
    spre[tid] += add;
    __syncthreads();
  }
  const int m = spre[511];
  const int pref = spre[tid] - mylen;

  for (int j = 0; j < len0; ++j) {
    unsigned int p = stage[base0 + j];
    raw[pref + j] = p;
    atomicAdd(&cnt[p >> 17], 1);
  }
  for (int j = 0; j < len1; ++j) {
    unsigned int p = stage[base1 + j];
    raw[pref + len0 + j] = p;
    atomicAdd(&cnt[p >> 17], 1);
  }
  __syncthreads();

  int v = 0;
  if (tid < BNODES) { v = cnt[tid]; ts[tid] = v; }
  __syncthreads();
  for (int o = 1; o < BNODES; o <<= 1) {
    int add = (tid >= o && tid < BNODES) ? ts[tid - o] : 0;
    __syncthreads();
    if (tid < BNODES) ts[tid] += add;
    __syncthreads();
  }
  if (tid < BNODES) {
    int excl = ts[tid] - v;
    int node = n0 + tid;
    float dv = rsqrtf((float)v + 1.0f);
    dinvL[tid] = dv;
    if (node < N_NODES) {
      off[node]  = b * BCAP + excl;
      edeg[node] = v;
      dinv[node] = dv;
    }
    cnt[tid] = excl;
  }
  __syncthreads();

  for (int i = tid; i < m; i += 512) {
    unsigned int p = raw[i];
    int pos = atomicAdd(&cnt[p >> 17], 1);
    if (pos < BCAP) sorted[pos] = (int)(p & SRC_MASK);
  }
  __syncthreads();

  int* out = eSrc + (size_t)b * BCAP;
  for (int i = tid; i < m; i += 512) out[i] = sorted[i];

  const int rows = min(BNODES, N_NODES - n0);
  for (int i = tid; i < rows * 64; i += 512) {
    int r = i >> 6;
    size_t g = (size_t)(n0 + r) * 64 + (i & 63);
    Xs[g] = f2bf(dinvL[r] * x[g]);
  }
}

// ---------------------------------------------------------------------------
// CSR aggregation (v3, memory-floor bound): one wave per node, 8 edges per
// uint4 gather, bf16 out. FETCH ~160MB/layer at ~3.3 TB/s (measured R10-R15).
// ---------------------------------------------------------------------------
__global__ __launch_bounds__(256) void agg_csr(
    const int* __restrict__ off, const int* __restrict__ edeg,
    const int* __restrict__ eSrc, const unsigned short* __restrict__ Xs,
    const float* __restrict__ dinv, unsigned short* __restrict__ agg) {
  const int wid = (blockIdx.x * 256 + threadIdx.x) >> 6;
  const int lane = threadIdx.x & 63;
  const int grp = lane >> 3, sub = lane & 7;
  if (wid >= N_NODES) return;
  const int s0 = off[wid];
  const int s1 = s0 + edeg[wid];
  const uint4* XsV = (const uint4*)Xs;

  float2 acc[4];
  {
    uint4 u = XsV[(size_t)wid * 8 + sub];
    if (grp != 0) { u.x = 0; u.y = 0; u.z = 0; u.w = 0; }
    acc[0] = bfpair(u.x);
    acc[1] = bfpair(u.y);
    acc[2] = bfpair(u.z);
    acc[3] = bfpair(u.w);
  }

  int e = s0;
  const int eend = s1 - ((s1 - s0) & 31);
  for (; e < eend; e += 32) {
    int sa = eSrc[e + grp];
    int sb = eSrc[e + 8 + grp];
    int sc = eSrc[e + 16 + grp];
    int sd = eSrc[e + 24 + grp];
    uint4 ua = XsV[(size_t)sa * 8 + sub];
    uint4 ub = XsV[(size_t)sb * 8 + sub];
    uint4 uc = XsV[(size_t)sc * 8 + sub];
    uint4 ud = XsV[(size_t)sd * 8 + sub];
    addp(acc, ua); addp(acc, ub); addp(acc, uc); addp(acc, ud);
  }
  if (e < s1) {
    const int lim = s1 - 1;
    int ea = e + grp, eb = e + 8 + grp, ec = e + 16 + grp, ed = e + 24 + grp;
    int sa = eSrc[min(ea, lim)];
    int sb = eSrc[min(eb, lim)];
    int sc = eSrc[min(ec, lim)];
    int sd = eSrc[min(ed, lim)];
    uint4 ua = XsV[(size_t)sa * 8 + sub];
    uint4 ub = XsV[(size_t)sb * 8 + sub];
    uint4 uc = XsV[(size_t)sc * 8 + sub];
    uint4 ud = XsV[(size_t)sd * 8 + sub];
    if (ea > lim) { ua.x = 0; ua.y = 0; ua.z = 0; ua.w = 0; }
    if (eb > lim) { ub.x = 0; ub.y = 0; ub.z = 0; ub.w = 0; }
    if (ec > lim) { uc.x = 0; uc.y = 0; uc.z = 0; uc.w = 0; }
    if (ed > lim) { ud.x = 0; ud.y = 0; ud.z = 0; ud.w = 0; }
    addp(acc, ua); addp(acc, ub); addp(acc, uc); addp(acc, ud);
  }

  #pragma unroll
  for (int mk = 8; mk <= 32; mk <<= 1) {
    #pragma unroll
    for (int i = 0; i < 4; ++i) {
      acc[i].x += __shfl_xor(acc[i].x, mk, 64);
      acc[i].y += __shfl_xor(acc[i].y, mk, 64);
    }
  }

  if (grp == 0) {
    float dt = dinv[wid];
    uint4 o;
    o.x = ((unsigned)f2bf(acc[0].y * dt) << 16) | f2bf(acc[0].x * dt);
    o.y = ((unsigned)f2bf(acc[1].y * dt) << 16) | f2bf(acc[1].x * dt);
    o.z = ((unsigned)f2bf(acc[2].y * dt) << 16) | f2bf(acc[2].x * dt);
    o.w = ((unsigned)f2bf(acc[3].y * dt) << 16) | f2bf(acc[3].x * dt);
    *(uint4*)(agg + (size_t)wid * 64 + sub * 8) = o;
  }
}

// ---------------------------------------------------------------------------
// MFMA GEMM: Yb(bf16)[128-row block] = A(bf16) @ WcB + bc, fused col stats.
// Stats line-padded: stats[j*16]=sum_j, stats[j*16+1]=sq_j (64 lines, not 4).
// ---------------------------------------------------------------------------
__global__ __launch_bounds__(256) void gemm_stats(
    const unsigned short* __restrict__ A, const unsigned int* __restrict__ WcB,
    const float* __restrict__ bc, unsigned short* __restrict__ Yb,
    float* __restrict__ stats) {
  const int tid = threadIdx.x;
  const int L = tid & 63, wv = tid >> 6;
  const int quad = L >> 4, l16 = L & 15;

  const bf16x8* Wv = (const bf16x8*)WcB;
  bf16x8 bfr[4][2];
  #pragma unroll
  for (int nt = 0; nt < 4; ++nt)
    #pragma unroll
    for (int kh = 0; kh < 2; ++kh)
      bfr[nt][kh] = Wv[(nt * 2 + kh) * 64 + L];
  float bcv[4];
  #pragma unroll
  for (int nt = 0; nt < 4; ++nt) bcv[nt] = bc[nt * 16 + l16];

  const bf16x8* Av = (const bf16x8*)A;
  float psum[4] = {0.f, 0.f, 0.f, 0.f}, psq[4] = {0.f, 0.f, 0.f, 0.f};

  #pragma unroll
  for (int loop = 0; loop < 2; ++loop) {
    const int rowbase = blockIdx.x * 128 + loop * 64 + wv * 16;
    const int m = min(rowbase + l16, N_NODES - 1);
    bf16x8 a0 = Av[(size_t)m * 8 + quad];
    bf16x8 a1 = Av[(size_t)m * 8 + 4 + quad];
    #pragma unroll
    for (int nt = 0; nt < 4; ++nt) {
      f32x4 acc = {0.f, 0.f, 0.f, 0.f};
      acc = __builtin_amdgcn_mfma_f32_16x16x32_bf16(a0, bfr[nt][0], acc, 0, 0, 0);
      acc = __builtin_amdgcn_mfma_f32_16x16x32_bf16(a1, bfr[nt][1], acc, 0, 0, 0);
      #pragma unroll
      for (int r = 0; r < 4; ++r) {
        int row = rowbase + quad * 4 + r;
        if (row < N_NODES) {
          float y = acc[r] + bcv[nt];
          Yb[(size_t)row * 64 + nt * 16 + l16] = f2bf(y);
          psum[nt] += y;
          psq[nt] += y * y;
        }
      }
    }
  }

  #pragma unroll
  for (int nt = 0; nt < 4; ++nt) {
    psum[nt] += __shfl_xor(psum[nt], 16, 64);
    psum[nt] += __shfl_xor(psum[nt], 32, 64);
    psq[nt]  += __shfl_xor(psq[nt], 16, 64);
    psq[nt]  += __shfl_xor(psq[nt], 32, 64);
  }
  __shared__ float rsum[4][64];
  __shared__ float rsq[4][64];
  if (L < 16) {
    #pragma unroll
    for (int nt = 0; nt < 4; ++nt) {
      rsum[wv][nt * 16 + L] = psum[nt];
      rsq[wv][nt * 16 + L]  = psq[nt];
    }
  }
  __syncthreads();
  if (tid < 64) {
    float s = rsum[0][tid] + rsum[1][tid] + rsum[2][tid] + rsum[3][tid];
    float q = rsq[0][tid] + rsq[1][tid] + rsq[2][tid] + rsq[3][tid];
    atomicAdd(&stats[tid * 16], s);       // one cacheline per column
    atomicAdd(&stats[tid * 16 + 1], q);
  }
}

// ---------------------------------------------------------------------------
// prescale_y (+inline finalize of layer-1 BN), in place over the Yb buffer
// ---------------------------------------------------------------------------
__global__ __launch_bounds__(256) void prescale_y(
    unsigned short* __restrict__ YbXs, const float* __restrict__ dinv,
    const float* __restrict__ stats, const float* __restrict__ g,
    const float* __restrict__ bt) {
  __shared__ float sa[64], sc[64];
  if (threadIdx.x < 64) {
    int j = threadIdx.x;
    float mu = stats[j * 16] * (1.0f / N_NODES);
    float var = stats[j * 16 + 1] * (1.0f / N_NODES) - mu * mu;
    float s = rsqrtf(var + EPS) * g[j];
    sa[j] = s;
    sc[j] = bt[j] - mu * s;
  }
  __syncthreads();
  int idx = blockIdx.x * blockDim.x + threadIdx.x;
  if (idx < N_NODES * D) {
    int i = idx >> 6, j = idx & 63;
    float y = bf2f(YbXs[idx]);
    YbXs[idx] = f2bf(dinv[i] * fmaxf(fmaf(y, sa[j], sc[j]), 0.f));
  }
}

// ---------------------------------------------------------------------------
// final_norm (+inline finalize of layer-2 BN): out = relu(Yb*a2 + c2), fp32
// ---------------------------------------------------------------------------
__global__ __launch_bounds__(256) void final_norm(
    const unsigned short* __restrict__ Yb, float* __restrict__ out,
    const float* __restrict__ stats, const float* __restrict__ g,
    const float* __restrict__ bt) {
  __shared__ float sa[64], sc[64];
  if (threadIdx.x < 64) {
    int j = threadIdx.x;
    float mu = stats[j * 16] * (1.0f / N_NODES);
    float var = stats[j * 16 + 1] * (1.0f / N_NODES) - mu * mu;
    float s = rsqrtf(var + EPS) * g[j];
    sa[j] = s;
    sc[j] = bt[j] - mu * s;
  }
  __syncthreads();
  int idx = blockIdx.x * blockDim.x + threadIdx.x;
  if (idx < N_NODES * D) {
    int j = idx & 63;
    out[idx] = fmaxf(fmaf(bf2f(Yb[idx]), sa[j], sc[j]), 0.f);
  }
}

extern "C" void kernel_launch(void* const* d_in, const int* in_sizes, int n_in,
                              void* d_out, int out_size, void* d_ws, size_t ws_size,
                              hipStream_t stream) {
  const float* x   = (const float*)d_in[0];
  const int*   src = (const int*)d_in[1];          // edge_index row 0
  const int*   dst = src + N_EDGES;                // edge_index row 1
  const float* W1  = (const float*)d_in[2];
  const float* b1  = (const float*)d_in[3];
  const float* fw1 = (const float*)d_in[4];
  const float* fb1 = (const float*)d_in[5];
  const float* g1  = (const float*)d_in[6];
  const float* bt1 = (const float*)d_in[7];
  const float* W2  = (const float*)d_in[8];
  const float* b2  = (const float*)d_in[9];
  const float* fw2 = (const float*)d_in[10];
  const float* fb2 = (const float*)d_in[11];
  const float* g2  = (const float*)d_in[12];
  const float* bt2 = (const float*)d_in[13];

  float* out = (float*)d_out;                      // N x 64 fp32

  // workspace (~43 MB). stage aliases aggb; XsYb doubles as the bf16 Y buffer.
  unsigned char* w = (unsigned char*)d_ws;
  unsigned int*   stage = (unsigned int*)w;              // NB_P1*4096 uints
  unsigned short* aggb  = (unsigned short*)w;            // N*64 bf16 (alias)
  size_t ofs = ((size_t)NB_P1 * P1_CHUNK * 4 + 255) & ~(size_t)255;
  float*          dinv  = (float*)(w + ofs);             // N floats
  unsigned short* XsYb  = (unsigned short*)(dinv + N_NODES);          // N*64 bf16
  int*            eSrc  = (int*)(XsYb + (size_t)N_NODES * D);         // NBUCK*BCAP ints
  int*            off   = eSrc + (size_t)NBUCK * BCAP;   // N ints
  int*            edeg  = off + N_NODES;                 // N ints
  unsigned short* tbl   = (unsigned short*)(edeg + N_NODES);          // NB_P1*784 ushort
  unsigned int* WcB1 = (unsigned int*)(tbl + (size_t)NB_P1 * TBL_STRIDE); // 2048
  float* bc1  = (float*)(WcB1 + 2048);             // 64
  unsigned int* WcB2 = (unsigned int*)(bc1 + 64);  // 2048
  float* bc2  = (float*)(WcB2 + 2048);             // 64
  float* stats  = bc2 + 64;                        // 2048 floats, line-padded
  float* stats1 = stats;                           // layer 1: [j*16]=sum,[j*16+1]=sq
  float* stats2 = stats + 1024;                    // layer 2

  const int nd = N_NODES * D;
  dim3 blk(256);

  // 1. weight fold + stats zero (3 blocks)
  combine_weights<<<3, blk, 0, stream>>>(W1, b1, fw1, fb1, W2, b2, fw2, fb2,
                                         WcB1, bc1, WcB2, bc2, stats);
  // 2-3. partition: block-local sort -> per-bucket node CSR (+L1 prescale)
  pass1_sort<<<NB_P1, blk, 0, stream>>>(src, dst, stage, tbl);
  pass2_sort<<<NBUCK, 512, 0, stream>>>(stage, tbl, eSrc, off, edeg, dinv, x, XsYb);
  // 4-6. layer 1
  agg_csr<<<(nd + 255) / 256, blk, 0, stream>>>(off, edeg, eSrc, XsYb, dinv, aggb);
  gemm_stats<<<(N_NODES + 127) / 128, blk, 0, stream>>>(aggb, WcB1, bc1, XsYb, stats1);
  prescale_y<<<(nd + 255) / 256, blk, 0, stream>>>(XsYb, dinv, stats1, g1, bt1);
  // 7-9. layer 2
  agg_csr<<<(nd + 255) / 256, blk, 0, stream>>>(off, edeg, eSrc, XsYb, dinv, aggb);
  gemm_stats<<<(N_NODES + 127) / 128, blk, 0, stream>>>(aggb, WcB2, bc2, XsYb, stats2);
  final_norm<<<(nd + 255) / 256, blk, 0, stream>>>(XsYb, out, stats2, g2, bt2);
}

// Round 17
// 335.652 us; speedup vs baseline: 1.3867x; 1.1392x over previous
//
#include <hip/hip_runtime.h>

#define N_NODES 100000
#define N_EDGES 3200000
#define D 64
#define EPS 1e-5f

#define BSHIFT 7
#define BNODES 128                                          // nodes per bucket
#define NBUCK ((N_NODES + BNODES - 1) / BNODES)             // 782
#define P1_CHUNK 4096
#define NB_P1 ((N_EDGES + P1_CHUNK - 1) / P1_CHUNK)         // 782
#define SRC_MASK 0x1FFFFu                                   // 17 bits >= 100000
#define BCAP 4480                                           // bucket region cap
#define TBL_STRIDE 784                                      // 783 entries + pad

typedef __attribute__((ext_vector_type(8))) short bf16x8;   // 8 bf16 = 4 VGPRs
typedef __attribute__((ext_vector_type(4))) float f32x4;

__device__ __forceinline__ unsigned short f2bf(float f) {
  unsigned int u = __float_as_uint(f);
  u += 0x7FFFu + ((u >> 16) & 1u);          // round to nearest even
  return (unsigned short)(u >> 16);
}
__device__ __forceinline__ float bf2f(unsigned short h) {
  return __uint_as_float(((unsigned int)h) << 16);
}
__device__ __forceinline__ float2 bfpair(unsigned int u) {
  return make_float2(__uint_as_float(u << 16), __uint_as_float(u & 0xFFFF0000u));
}
__device__ __forceinline__ void addp(float2 a[4], uint4 u) {
  a[0] += bfpair(u.x);
  a[1] += bfpair(u.y);
  a[2] += bfpair(u.z);
  a[3] += bfpair(u.w);
}

// ---------------------------------------------------------------------------
// blocks 0,1: fold GCNConv+FC into 64x64, emit MFMA-B-swizzled bf16 + bc.
// block 2: zero BN stat accumulators (256 floats, PACKED — R14/R16 showed
// line-padded atomic targets cost ~40us; wave-coalesced packed lines win).
// ---------------------------------------------------------------------------
__global__ __launch_bounds__(256) void combine_weights(
    const float* __restrict__ W1, const float* __restrict__ b1,
    const float* __restrict__ fw1, const float* __restrict__ fb1,
    const float* __restrict__ W2, const float* __restrict__ b2,
    const float* __restrict__ fw2, const float* __restrict__ fb2,
    unsigned int* __restrict__ WcB1, float* __restrict__ bc1,
    unsigned int* __restrict__ WcB2, float* __restrict__ bc2,
    float* __restrict__ stats) {
  if (blockIdx.x == 2) {
    if (threadIdx.x < 256) stats[threadIdx.x] = 0.0f;
    return;
  }
  const float* W  = blockIdx.x ? W2  : W1;
  const float* fw = blockIdx.x ? fw2 : fw1;
  const float* b  = blockIdx.x ? b2  : b1;
  const float* fb = blockIdx.x ? fb2 : fb1;
  unsigned int* WcB = blockIdx.x ? WcB2 : WcB1;
  float* bc = blockIdx.x ? bc2 : bc1;

  __shared__ float sW[64 * 64];
  __shared__ float sf[64 * 64];
  __shared__ float sC[64 * 64];
  for (int i = threadIdx.x; i < 4096; i += 256) { sW[i] = W[i]; sf[i] = fw[i]; }
  __syncthreads();
  for (int o = threadIdx.x; o < 4096; o += 256) {
    int i = o >> 6, j = o & 63;
    float acc = 0.f;
    #pragma unroll
    for (int k = 0; k < 64; ++k) acc += sW[i * 64 + k] * sf[k * 64 + j];
    sC[o] = acc;
  }
  __syncthreads();
  // B-fragment swizzle: frag f=(nt*2+kh), lane L, elem j -> B[(L>>4)*8+j+kh*32][nt*16+(L&15)]
  for (int o = threadIdx.x; o < 2048; o += 256) {
    int jj = o & 3, L = (o >> 2) & 63, kh = (o >> 8) & 1, nt = o >> 9;
    int k0 = (L >> 4) * 8 + jj * 2 + kh * 32;
    int n  = nt * 16 + (L & 15);
    unsigned int lo = f2bf(sC[k0 * 64 + n]);
    unsigned int hi = f2bf(sC[(k0 + 1) * 64 + n]);
    WcB[o] = (hi << 16) | lo;
  }
  if (threadIdx.x < 64) {
    int j = threadIdx.x;
    float acc = fb[j];
    #pragma unroll
    for (int k = 0; k < 64; ++k) acc += b[k] * sf[k * 64 + j];
    bc[j] = acc;
  }
}

// ---------------------------------------------------------------------------
// Pass 1: block-local counting sort of a 4096-edge chunk by 128-node bucket.
// 782 blocks x 256 threads, lean 20.5 KB LDS (~7 resident blocks/CU).
// ---------------------------------------------------------------------------
__global__ __launch_bounds__(256) void pass1_sort(
    const int* __restrict__ src, const int* __restrict__ dst,
    unsigned int* __restrict__ stage, unsigned short* __restrict__ tbl) {
  __shared__ unsigned int hist[NBUCK];
  __shared__ unsigned int ts[256];
  __shared__ unsigned int sorted[P1_CHUNK];
  const int tid = threadIdx.x;
  const int e0 = blockIdx.x * P1_CHUNK;

  for (int b = tid; b < NBUCK; b += 256) hist[b] = 0;
  __syncthreads();

  int dreg[16];                               // dst cached -> no second dst read
  #pragma unroll
  for (int k = 0; k < 16; ++k) {
    int e = e0 + k * 256 + tid;
    int d = (e < N_EDGES) ? dst[e] : -1;
    dreg[k] = d;
    if (d >= 0) atomicAdd(&hist[((unsigned)d) >> BSHIFT], 1u);
  }
  __syncthreads();

  unsigned int v[4], run = 0;
  #pragma unroll
  for (int j = 0; j < 4; ++j) {
    int bk = 4 * tid + j;
    unsigned int h = (bk < NBUCK) ? hist[bk] : 0u;
    v[j] = run;
    run += h;
  }
  ts[tid] = run;
  __syncthreads();
  for (int o = 1; o < 256; o <<= 1) {
    unsigned int add = (tid >= o) ? ts[tid - o] : 0u;
    __syncthreads();
    ts[tid] += add;
    __syncthreads();
  }
  const unsigned int excl = ts[tid] - run;
  const unsigned int m = ts[255];
  unsigned short* trow = tbl + (size_t)blockIdx.x * TBL_STRIDE;
  #pragma unroll
  for (int j = 0; j < 4; ++j) {
    int bk = 4 * tid + j;
    if (bk < NBUCK) {
      unsigned int o = excl + v[j];
      hist[bk] = o;
      trow[bk] = (unsigned short)o;
    }
  }
  if (tid == 0) trow[NBUCK] = (unsigned short)m;
  __syncthreads();

  #pragma unroll
  for (int k = 0; k < 16; ++k) {
    int e = e0 + k * 256 + tid;
    int t = dreg[k];
    if (t >= 0) {
      unsigned int pos = atomicAdd(&hist[((unsigned)t) >> BSHIFT], 1u);
      sorted[pos] = (((unsigned)(t & (BNODES - 1))) << 17) | (unsigned)src[e];
    }
  }
  __syncthreads();

  unsigned int* so = stage + (size_t)blockIdx.x * P1_CHUNK;
  for (int i = tid; i < (int)m; i += 256) so[i] = sorted[i];
}

// ---------------------------------------------------------------------------
// Pass 2: paired-segment gather (thread owns chunk-segments 2t, 2t+1), single
// read of stage, LDS counting sort to node CSR. Emits eSrc, off, edeg, dinv,
// and the fused layer-1 prescale Xs.
// ---------------------------------------------------------------------------
__global__ __launch_bounds__(512) void pass2_sort(
    const unsigned int* __restrict__ stage, const unsigned short* __restrict__ tbl,
    int* __restrict__ eSrc, int* __restrict__ off, int* __restrict__ edeg,
    float* __restrict__ dinv, const float* __restrict__ x,
    unsigned short* __restrict__ Xs) {
  __shared__ int spre[512];
  __shared__ int cnt[BNODES];
  __shared__ int ts[BNODES];
  __shared__ float dinvL[BNODES];
  __shared__ unsigned int raw[BCAP];
  __shared__ int sorted[BCAP];
  const int b = blockIdx.x, tid = threadIdx.x;
  const int n0 = b * BNODES;

  int base0 = 0, base1 = 0, len0 = 0, len1 = 0;
  {
    int s0 = 2 * tid, s1 = 2 * tid + 1;
    if (s0 < NB_P1) {
      const unsigned short* trow = tbl + (size_t)s0 * TBL_STRIDE;
      int o0 = trow[b], o1 = trow[b + 1];
      base0 = s0 * P1_CHUNK + o0;
      len0 = o1 - o0;
    }
    if (s1 < NB_P1) {
      const unsigned short* trow = tbl + (size_t)s1 * TBL_STRIDE;
      int o0 = trow[b], o1 = trow[b + 1];
      base1 = s1 * P1_CHUNK + o0;
      len1 = o1 - o0;
    }
  }
  if (tid < BNODES) cnt[tid] = 0;
  const int mylen = len0 + len1;
  spre[tid] = mylen;
  __syncthreads();
  for (int o = 1; o < 512; o <<= 1) {
    int add = (tid >= o) ? spre[tid - o] : 0;
    __syncthreads();
    spre[tid] += add;
    __syncthreads();
  }
  const int m = spre[511];
  const int pref = spre[tid] - mylen;

  for (int j = 0; j < len0; ++j) {
    unsigned int p = stage[base0 + j];
    raw[pref + j] = p;
    atomicAdd(&cnt[p >> 17], 1);
  }
  for (int j = 0; j < len1; ++j) {
    unsigned int p = stage[base1 + j];
    raw[pref + len0 + j] = p;
    atomicAdd(&cnt[p >> 17], 1);
  }
  __syncthreads();

  int v = 0;
  if (tid < BNODES) { v = cnt[tid]; ts[tid] = v; }
  __syncthreads();
  for (int o = 1; o < BNODES; o <<= 1) {
    int add = (tid >= o && tid < BNODES) ? ts[tid - o] : 0;
    __syncthreads();
    if (tid < BNODES) ts[tid] += add;
    __syncthreads();
  }
  if (tid < BNODES) {
    int excl = ts[tid] - v;
    int node = n0 + tid;
    float dv = rsqrtf((float)v + 1.0f);
    dinvL[tid] = dv;
    if (node < N_NODES) {
      off[node]  = b * BCAP + excl;
      edeg[node] = v;
      dinv[node] = dv;
    }
    cnt[tid] = excl;
  }
  __syncthreads();

  for (int i = tid; i < m; i += 512) {
    unsigned int p = raw[i];
    int pos = atomicAdd(&cnt[p >> 17], 1);
    if (pos < BCAP) sorted[pos] = (int)(p & SRC_MASK);
  }
  __syncthreads();

  int* out = eSrc + (size_t)b * BCAP;
  for (int i = tid; i < m; i += 512) out[i] = sorted[i];

  const int rows = min(BNODES, N_NODES - n0);
  for (int i = tid; i < rows * 64; i += 512) {
    int r = i >> 6;
    size_t g = (size_t)(n0 + r) * 64 + (i & 63);
    Xs[g] = f2bf(dinvL[r] * x[g]);
  }
}

// ---------------------------------------------------------------------------
// CSR aggregation (v3, memory-floor bound): one wave per node, 8 edges per
// uint4 gather, bf16 out. FETCH ~160MB/layer at ~3.3 TB/s (measured R10-R16).
// ---------------------------------------------------------------------------
__global__ __launch_bounds__(256) void agg_csr(
    const int* __restrict__ off, const int* __restrict__ edeg,
    const int* __restrict__ eSrc, const unsigned short* __restrict__ Xs,
    const float* __restrict__ dinv, unsigned short* __restrict__ agg) {
  const int wid = (blockIdx.x * 256 + threadIdx.x) >> 6;
  const int lane = threadIdx.x & 63;
  const int grp = lane >> 3, sub = lane & 7;
  if (wid >= N_NODES) return;
  const int s0 = off[wid];
  const int s1 = s0 + edeg[wid];
  const uint4* XsV = (const uint4*)Xs;

  float2 acc[4];
  {
    uint4 u = XsV[(size_t)wid * 8 + sub];
    if (grp != 0) { u.x = 0; u.y = 0; u.z = 0; u.w = 0; }
    acc[0] = bfpair(u.x);
    acc[1] = bfpair(u.y);
    acc[2] = bfpair(u.z);
    acc[3] = bfpair(u.w);
  }

  int e = s0;
  const int eend = s1 - ((s1 - s0) & 31);
  for (; e < eend; e += 32) {
    int sa = eSrc[e + grp];
    int sb = eSrc[e + 8 + grp];
    int sc = eSrc[e + 16 + grp];
    int sd = eSrc[e + 24 + grp];
    uint4 ua = XsV[(size_t)sa * 8 + sub];
    uint4 ub = XsV[(size_t)sb * 8 + sub];
    uint4 uc = XsV[(size_t)sc * 8 + sub];
    uint4 ud = XsV[(size_t)sd * 8 + sub];
    addp(acc, ua); addp(acc, ub); addp(acc, uc); addp(acc, ud);
  }
  if (e < s1) {
    const int lim = s1 - 1;
    int ea = e + grp, eb = e + 8 + grp, ec = e + 16 + grp, ed = e + 24 + grp;
    int sa = eSrc[min(ea, lim)];
    int sb = eSrc[min(eb, lim)];
    int sc = eSrc[min(ec, lim)];
    int sd = eSrc[min(ed, lim)];
    uint4 ua = XsV[(size_t)sa * 8 + sub];
    uint4 ub = XsV[(size_t)sb * 8 + sub];
    uint4 uc = XsV[(size_t)sc * 8 + sub];
    uint4 ud = XsV[(size_t)sd * 8 + sub];
    if (ea > lim) { ua.x = 0; ua.y = 0; ua.z = 0; ua.w = 0; }
    if (eb > lim) { ub.x = 0; ub.y = 0; ub.z = 0; ub.w = 0; }
    if (ec > lim) { uc.x = 0; uc.y = 0; uc.z = 0; uc.w = 0; }
    if (ed > lim) { ud.x = 0; ud.y = 0; ud.z = 0; ud.w = 0; }
    addp(acc, ua); addp(acc, ub); addp(acc, uc); addp(acc, ud);
  }

  #pragma unroll
  for (int mk = 8; mk <= 32; mk <<= 1) {
    #pragma unroll
    for (int i = 0; i < 4; ++i) {
      acc[i].x += __shfl_xor(acc[i].x, mk, 64);
      acc[i].y += __shfl_xor(acc[i].y, mk, 64);
    }
  }

  if (grp == 0) {
    float dt = dinv[wid];
    uint4 o;
    o.x = ((unsigned)f2bf(acc[0].y * dt) << 16) | f2bf(acc[0].x * dt);
    o.y = ((unsigned)f2bf(acc[1].y * dt) << 16) | f2bf(acc[1].x * dt);
    o.z = ((unsigned)f2bf(acc[2].y * dt) << 16) | f2bf(acc[2].x * dt);
    o.w = ((unsigned)f2bf(acc[3].y * dt) << 16) | f2bf(acc[3].x * dt);
    *(uint4*)(agg + (size_t)wid * 64 + sub * 8) = o;
  }
}

// ---------------------------------------------------------------------------
// MFMA GEMM: Yb(bf16)[128-row block] = A(bf16) @ WcB + bc, fused col stats.
// Packed contiguous stat atomics (R12-proven; padding regresses ~40us).
// ---------------------------------------------------------------------------
__global__ __launch_bounds__(256) void gemm_stats(
    const unsigned short* __restrict__ A, const unsigned int* __restrict__ WcB,
    const float* __restrict__ bc, unsigned short* __restrict__ Yb,
    float* __restrict__ colsum, float* __restrict__ colsq) {
  const int tid = threadIdx.x;
  const int L = tid & 63, wv = tid >> 6;
  const int quad = L >> 4, l16 = L & 15;

  const bf16x8* Wv = (const bf16x8*)WcB;
  bf16x8 bfr[4][2];
  #pragma unroll
  for (int nt = 0; nt < 4; ++nt)
    #pragma unroll
    for (int kh = 0; kh < 2; ++kh)
      bfr[nt][kh] = Wv[(nt * 2 + kh) * 64 + L];
  float bcv[4];
  #pragma unroll
  for (int nt = 0; nt < 4; ++nt) bcv[nt] = bc[nt * 16 + l16];

  const bf16x8* Av = (const bf16x8*)A;
  float psum[4] = {0.f, 0.f, 0.f, 0.f}, psq[4] = {0.f, 0.f, 0.f, 0.f};

  #pragma unroll
  for (int loop = 0; loop < 2; ++loop) {
    const int rowbase = blockIdx.x * 128 + loop * 64 + wv * 16;
    const int m = min(rowbase + l16, N_NODES - 1);
    bf16x8 a0 = Av[(size_t)m * 8 + quad];
    bf16x8 a1 = Av[(size_t)m * 8 + 4 + quad];
    #pragma unroll
    for (int nt = 0; nt < 4; ++nt) {
      f32x4 acc = {0.f, 0.f, 0.f, 0.f};
      acc = __builtin_amdgcn_mfma_f32_16x16x32_bf16(a0, bfr[nt][0], acc, 0, 0, 0);
      acc = __builtin_amdgcn_mfma_f32_16x16x32_bf16(a1, bfr[nt][1], acc, 0, 0, 0);
      #pragma unroll
      for (int r = 0; r < 4; ++r) {
        int row = rowbase + quad * 4 + r;
        if (row < N_NODES) {
          float y = acc[r] + bcv[nt];
          Yb[(size_t)row * 64 + nt * 16 + l16] = f2bf(y);
          psum[nt] += y;
          psq[nt] += y * y;
        }
      }
    }
  }

  #pragma unroll
  for (int nt = 0; nt < 4; ++nt) {
    psum[nt] += __shfl_xor(psum[nt], 16, 64);
    psum[nt] += __shfl_xor(psum[nt], 32, 64);
    psq[nt]  += __shfl_xor(psq[nt], 16, 64);
    psq[nt]  += __shfl_xor(psq[nt], 32, 64);
  }
  __shared__ float rsum[4][64];
  __shared__ float rsq[4][64];
  if (L < 16) {
    #pragma unroll
    for (int nt = 0; nt < 4; ++nt) {
      rsum[wv][nt * 16 + L] = psum[nt];
      rsq[wv][nt * 16 + L]  = psq[nt];
    }
  }
  __syncthreads();
  if (tid < 64) {
    float s = rsum[0][tid] + rsum[1][tid] + rsum[2][tid] + rsum[3][tid];
    float q = rsq[0][tid] + rsq[1][tid] + rsq[2][tid] + rsq[3][tid];
    atomicAdd(&colsum[tid], s);
    atomicAdd(&colsq[tid], q);
  }
}

// ---------------------------------------------------------------------------
// prescale_y (vectorized, uint4 = 8 bf16 per thread):
//   Xs = bf16( dinv[row] * relu(Yb*a1+c1) ), in place over the Yb buffer
// ---------------------------------------------------------------------------
__global__ __launch_bounds__(256) void prescale_y(
    unsigned short* __restrict__ YbXs, const float* __restrict__ dinv,
    const float* __restrict__ colsum, const float* __restrict__ colsq,
    const float* __restrict__ g, const float* __restrict__ bt) {
  __shared__ float sa[64], sc[64];
  if (threadIdx.x < 64) {
    int j = threadIdx.x;
    float mu = colsum[j] * (1.0f / N_NODES);
    float var = colsq[j] * (1.0f / N_NODES) - mu * mu;
    float s = rsqrtf(var + EPS) * g[j];
    sa[j] = s;
    sc[j] = bt[j] - mu * s;
  }
  __syncthreads();
  int idx = blockIdx.x * blockDim.x + threadIdx.x;     // uint4 index
  if (idx < N_NODES * 8) {
    int r = idx >> 3, c0 = (idx & 7) * 8;
    float dv = dinv[r];
    uint4 u = ((const uint4*)YbXs)[idx];
    float2 p0 = bfpair(u.x), p1 = bfpair(u.y), p2 = bfpair(u.z), p3 = bfpair(u.w);
    p0.x = dv * fmaxf(fmaf(p0.x, sa[c0    ], sc[c0    ]), 0.f);
    p0.y = dv * fmaxf(fmaf(p0.y, sa[c0 + 1], sc[c0 + 1]), 0.f);
    p1.x = dv * fmaxf(fmaf(p1.x, sa[c0 + 2], sc[c0 + 2]), 0.f);
    p1.y = dv * fmaxf(fmaf(p1.y, sa[c0 + 3], sc[c0 + 3]), 0.f);
    p2.x = dv * fmaxf(fmaf(p2.x, sa[c0 + 4], sc[c0 + 4]), 0.f);
    p2.y = dv * fmaxf(fmaf(p2.y, sa[c0 + 5], sc[c0 + 5]), 0.f);
    p3.x = dv * fmaxf(fmaf(p3.x, sa[c0 + 6], sc[c0 + 6]), 0.f);
    p3.y = dv * fmaxf(fmaf(p3.y, sa[c0 + 7], sc[c0 + 7]), 0.f);
    uint4 o;
    o.x = ((unsigned)f2bf(p0.y) << 16) | f2bf(p0.x);
    o.y = ((unsigned)f2bf(p1.y) << 16) | f2bf(p1.x);
    o.z = ((unsigned)f2bf(p2.y) << 16) | f2bf(p2.x);
    o.w = ((unsigned)f2bf(p3.y) << 16) | f2bf(p3.x);
    ((uint4*)YbXs)[idx] = o;
  }
}

// ---------------------------------------------------------------------------
// final_norm (vectorized): out = fp32 relu(Yb*a2 + c2), 8 elems per thread
// ---------------------------------------------------------------------------
__global__ __launch_bounds__(256) void final_norm(
    const unsigned short* __restrict__ Yb, float* __restrict__ out,
    const float* __restrict__ colsum, const float* __restrict__ colsq,
    const float* __restrict__ g, const float* __restrict__ bt) {
  __shared__ float sa[64], sc[64];
  if (threadIdx.x < 64) {
    int j = threadIdx.x;
    float mu = colsum[j] * (1.0f / N_NODES);
    float var = colsq[j] * (1.0f / N_NODES) - mu * mu;
    float s = rsqrtf(var + EPS) * g[j];
    sa[j] = s;
    sc[j] = bt[j] - mu * s;
  }
  __syncthreads();
  int idx = blockIdx.x * blockDim.x + threadIdx.x;     // uint4 index
  if (idx < N_NODES * 8) {
    int c0 = (idx & 7) * 8;
    uint4 u = ((const uint4*)Yb)[idx];
    float2 p0 = bfpair(u.x), p1 = bfpair(u.y), p2 = bfpair(u.z), p3 = bfpair(u.w);
    float4 o0, o1;
    o0.x = fmaxf(fmaf(p0.x, sa[c0    ], sc[c0    ]), 0.f);
    o0.y = fmaxf(fmaf(p0.y, sa[c0 + 1], sc[c0 + 1]), 0.f);
    o0.z = fmaxf(fmaf(p1.x, sa[c0 + 2], sc[c0 + 2]), 0.f);
    o0.w = fmaxf(fmaf(p1.y, sa[c0 + 3], sc[c0 + 3]), 0.f);
    o1.x = fmaxf(fmaf(p2.x, sa[c0 + 4], sc[c0 + 4]), 0.f);
    o1.y = fmaxf(fmaf(p2.y, sa[c0 + 5], sc[c0 + 5]), 0.f);
    o1.z = fmaxf(fmaf(p3.x, sa[c0 + 6], sc[c0 + 6]), 0.f);
    o1.w = fmaxf(fmaf(p3.y, sa[c0 + 7], sc[c0 + 7]), 0.f);
    ((float4*)out)[idx * 2] = o0;
    ((float4*)out)[idx * 2 + 1] = o1;
  }
}

extern "C" void kernel_launch(void* const* d_in, const int* in_sizes, int n_in,
                              void* d_out, int out_size, void* d_ws, size_t ws_size,
                              hipStream_t stream) {
  const float* x   = (const float*)d_in[0];
  const int*   src = (const int*)d_in[1];          // edge_index row 0
  const int*   dst = src + N_EDGES;                // edge_index row 1
  const float* W1  = (const float*)d_in[2];
  const float* b1  = (const float*)d_in[3];
  const float* fw1 = (const float*)d_in[4];
  const float* fb1 = (const float*)d_in[5];
  const float* g1  = (const float*)d_in[6];
  const float* bt1 = (const float*)d_in[7];
  const float* W2  = (const float*)d_in[8];
  const float* b2  = (const float*)d_in[9];
  const float* fw2 = (const float*)d_in[10];
  const float* fb2 = (const float*)d_in[11];
  const float* g2  = (const float*)d_in[12];
  const float* bt2 = (const float*)d_in[13];

  float* out = (float*)d_out;                      // N x 64 fp32

  // workspace (~43 MB). stage aliases aggb; XsYb doubles as the bf16 Y buffer.
  unsigned char* w = (unsigned char*)d_ws;
  unsigned int*   stage = (unsigned int*)w;              // NB_P1*4096 uints
  unsigned short* aggb  = (unsigned short*)w;            // N*64 bf16 (alias)
  size_t ofs = ((size_t)NB_P1 * P1_CHUNK * 4 + 255) & ~(size_t)255;
  float*          dinv  = (float*)(w + ofs);             // N floats
  unsigned short* XsYb  = (unsigned short*)(dinv + N_NODES);          // N*64 bf16
  int*            eSrc  = (int*)(XsYb + (size_t)N_NODES * D);         // NBUCK*BCAP ints
  int*            off   = eSrc + (size_t)NBUCK * BCAP;   // N ints
  int*            edeg  = off + N_NODES;                 // N ints
  unsigned short* tbl   = (unsigned short*)(edeg + N_NODES);          // NB_P1*784 ushort
  unsigned int* WcB1 = (unsigned int*)(tbl + (size_t)NB_P1 * TBL_STRIDE); // 2048
  float* bc1  = (float*)(WcB1 + 2048);             // 64
  unsigned int* WcB2 = (unsigned int*)(bc1 + 64);  // 2048
  float* bc2  = (float*)(WcB2 + 2048);             // 64
  float* sum1 = bc2 + 64;                          // 64  (sum1..sq2 contiguous 256)
  float* sq1  = sum1 + 64;
  float* sum2 = sq1 + 64;
  float* sq2  = sum2 + 64;

  const int nd = N_NODES * D;
  const int nv = N_NODES * 8;                      // uint4 count for elementwise
  dim3 blk(256);

  // 1. weight fold + stats zero (3 blocks)
  combine_weights<<<3, blk, 0, stream>>>(W1, b1, fw1, fb1, W2, b2, fw2, fb2,
                                         WcB1, bc1, WcB2, bc2, sum1);
  // 2-3. partition: block-local sort -> per-bucket node CSR (+L1 prescale)
  pass1_sort<<<NB_P1, blk, 0, stream>>>(src, dst, stage, tbl);
  pass2_sort<<<NBUCK, 512, 0, stream>>>(stage, tbl, eSrc, off, edeg, dinv, x, XsYb);
  // 4-6. layer 1
  agg_csr<<<(nd + 255) / 256, blk, 0, stream>>>(off, edeg, eSrc, XsYb, dinv, aggb);
  gemm_stats<<<(N_NODES + 127) / 128, blk, 0, stream>>>(aggb, WcB1, bc1, XsYb, sum1, sq1);
  prescale_y<<<(nv + 255) / 256, blk, 0, stream>>>(XsYb, dinv, sum1, sq1, g1, bt1);
  // 7-9. layer 2
  agg_csr<<<(nd + 255) / 256, blk, 0, stream>>>(off, edeg, eSrc, XsYb, dinv, aggb);
  gemm_stats<<<(N_NODES + 127) / 128, blk, 0, stream>>>(aggb, WcB2, bc2, XsYb, sum2, sq2);
  final_norm<<<(nv + 255) / 256, blk, 0, stream>>>(XsYb, out, sum2, sq2, g2, bt2);
}